// Round 7
// baseline (703.118 us; speedup 1.0000x reference)
//
#include <hip/hip_runtime.h>
#include <math.h>

#define NINST 4096

typedef _Float16 half8 __attribute__((ext_vector_type(8)));
typedef _Float16 half4 __attribute__((ext_vector_type(4)));
typedef float floatx4 __attribute__((ext_vector_type(4)));

// ---------------------------------------------------------------------------
// xform_w12: w1 (36,3,4,4) -> w1t [48 oc][64], k = ky*16+kx*4+ic
//            w2 (48,36,3,3) -> w2t [3 ky][48 oc][128], k = kx*40+ic (k<120)
// zero-padded elsewhere. 64 blocks (grid-stride).
// ---------------------------------------------------------------------------
__global__ void xform_w12(const float* __restrict__ w1, const float* __restrict__ w2,
                          _Float16* __restrict__ w1t, _Float16* __restrict__ w2t) {
  for (int i = blockIdx.x * 256 + threadIdx.x; i < 48 * 64; i += gridDim.x * 256) {
    const int oc = i >> 6, k = i & 63;
    const int ky = k >> 4, r = k & 15, kx = r >> 2, ic = r & 3;
    float v = 0.f;
    if (oc < 36 && ic < 3) v = w1[((oc * 3 + ic) * 4 + ky) * 4 + kx];
    w1t[i] = (_Float16)v;
  }
  for (int i = blockIdx.x * 256 + threadIdx.x; i < 3 * 48 * 128; i += gridDim.x * 256) {
    const int ky = i / 6144, r = i % 6144;
    const int oc = r >> 7, k = r & 127;
    float v = 0.f;
    if (k < 120) {
      const int kx = k / 40, ic = k % 40;
      if (ic < 36) v = w2[((oc * 36 + ic) * 3 + ky) * 3 + kx];
    }
    w2t[i] = (_Float16)v;
  }
}

// ---------------------------------------------------------------------------
// MFMA conv, persistent: 1024 blocks x 4 instances, all co-resident (4/CU).
// Pipeline: x(i+1) prefetched into REGISTERS while conv of i runs, so barriers
// only drain LDS on the critical path. 3 barriers per instance.
// LDS: x_s 8KB + h1_s 15.7KB + h2_s 3.4KB = 27.4KB.
// ---------------------------------------------------------------------------
__launch_bounds__(256, 4)
__global__ void conv_fused(const float* __restrict__ x,
                           const _Float16* __restrict__ w1t_g,
                           const _Float16* __restrict__ w2t_g,
                           const float* __restrict__ b1, const float* __restrict__ b2,
                           _Float16* __restrict__ emb) {
  __shared__ __align__(16) _Float16 x_s[4096];      // [1024 pix][4 ch]
  __shared__ __align__(16) _Float16 h1_s[7856];     // [196 pix][40 ic] + 16 pad
  __shared__ __align__(16) _Float16 h2_s[1728];     // epilogue staging

  const int tid = threadIdx.x;
  const int lane = tid & 63, wave = tid >> 6;
  const int quad = lane >> 4, l15 = lane & 15;
  const int n0 = blockIdx.x * 4;

  float bia2[3];
#pragma unroll
  for (int nt = 0; nt < 3; nt++) bia2[nt] = b2[nt * 16 + l15];

  // prefetch x for instance 0: thread handles pixels 4t..4t+3, 3 channels
  floatx4 xr0, xr1, xr2;
  {
    const float* xb = x + (size_t)n0 * 3072 + tid * 4;
    xr0 = __builtin_nontemporal_load((const floatx4*)(xb));
    xr1 = __builtin_nontemporal_load((const floatx4*)(xb + 1024));
    xr2 = __builtin_nontemporal_load((const floatx4*)(xb + 2048));
  }

  for (int i = 0; i < 4; i++) {
    // ---- store x regs -> x_s channel-last ----
    {
      half8 pk0, pk1;
      pk0[0] = (_Float16)xr0[0]; pk0[1] = (_Float16)xr1[0]; pk0[2] = (_Float16)xr2[0]; pk0[3] = (_Float16)0.f;
      pk0[4] = (_Float16)xr0[1]; pk0[5] = (_Float16)xr1[1]; pk0[6] = (_Float16)xr2[1]; pk0[7] = (_Float16)0.f;
      pk1[0] = (_Float16)xr0[2]; pk1[1] = (_Float16)xr1[2]; pk1[2] = (_Float16)xr2[2]; pk1[3] = (_Float16)0.f;
      pk1[4] = (_Float16)xr0[3]; pk1[5] = (_Float16)xr1[3]; pk1[6] = (_Float16)xr2[3]; pk1[7] = (_Float16)0.f;
      *(half8*)&x_s[tid * 16] = pk0;
      *(half8*)&x_s[tid * 16 + 8] = pk1;
      if (i == 0 && tid < 16) h1_s[7840 + tid] = (_Float16)0.f;  // zero overrun pad
    }
    __syncthreads();   // x ready (LDS drain only)

    // ---- prefetch next instance's x into regs (hidden behind conv work) ----
    if (i < 3) {
      const float* xn = x + (size_t)(n0 + i + 1) * 3072 + tid * 4;
      xr0 = __builtin_nontemporal_load((const floatx4*)(xn));
      xr1 = __builtin_nontemporal_load((const floatx4*)(xn + 1024));
      xr2 = __builtin_nontemporal_load((const floatx4*)(xn + 2048));
    }

    // ---- conv1: M=784, N=48(36), K=64(48) -> h1 pooled+relu ----
    {
      half8 bc[2][3];
#pragma unroll
      for (int c = 0; c < 2; c++)
#pragma unroll
        for (int nt = 0; nt < 3; nt++)
          bc[c][nt] = *(const half8*)&w1t_g[(nt * 16 + l15) * 64 + c * 32 + quad * 8];
      float bia[3];
#pragma unroll
      for (int nt = 0; nt < 3; nt++) {
        const int oc = nt * 16 + l15;
        bia[nt] = (oc < 36) ? b1[oc] : 0.f;
      }
      for (int mt = wave; mt < 49; mt += 4) {
        const int mA = mt * 16 + l15;
        const int ppA = mA >> 2, dA = mA & 3;
        const int yA = 2 * (ppA / 14) + (dA >> 1);
        const int xA = 2 * (ppA % 14) + (dA & 1);
        floatx4 a1[3];
#pragma unroll
        for (int nt = 0; nt < 3; nt++)
#pragma unroll
          for (int r = 0; r < 4; r++) a1[nt][r] = 0.f;
#pragma unroll
        for (int c = 0; c < 2; c++) {
          const int row = yA + c * 2 + (quad >> 1);
          const half8 af = *(const half8*)&x_s[row * 128 + xA * 4 + (quad & 1) * 8];
#pragma unroll
          for (int nt = 0; nt < 3; nt++)
            a1[nt] = __builtin_amdgcn_mfma_f32_16x16x32_f16(af, bc[c][nt], a1[nt], 0, 0, 0);
        }
        const int ppC = mt * 4 + quad;
#pragma unroll
        for (int nt = 0; nt < 3; nt++) {
          const int oc = nt * 16 + l15;
          float v = fmaxf(fmaxf(a1[nt][0], a1[nt][1]), fmaxf(a1[nt][2], a1[nt][3])) + bia[nt];
          v = fmaxf(v, 0.f);
          if (oc < 40) h1_s[ppC * 40 + oc] = (_Float16)v;  // oc 36..39 write pad zeros
        }
      }
    }
    __syncthreads();   // h1 ready (also absorbs x-prefetch drain, ~conv1-time later)

    // ---- conv2: M=144, N=48, K=3ky x 128(120) ----
    floatx4 acc2[3][3];
#pragma unroll
    for (int a = 0; a < 3; a++)
#pragma unroll
      for (int j = 0; j < 3; j++)
#pragma unroll
        for (int r = 0; r < 4; r++) acc2[a][j][r] = 0.f;

    for (int ky = 0; ky < 3; ky++) {
      half8 bc2[4][3];
#pragma unroll
      for (int c = 0; c < 4; c++)
#pragma unroll
        for (int nt = 0; nt < 3; nt++)
          bc2[c][nt] = *(const half8*)&w2t_g[ky * 6144 + (nt * 16 + l15) * 128 + c * 32 + quad * 8];
      int mi = 0;
      for (int mt = wave; mt < 9; mt += 4, mi++) {
        const int mA = mt * 16 + l15;
        const int ppA = mA >> 2, dA = mA & 3;
        const int y2 = 2 * (ppA / 6) + (dA >> 1);
        const int x2 = 2 * (ppA % 6) + (dA & 1);
        const int rb = ((y2 + ky) * 14 + x2) * 40;
#pragma unroll
        for (int c = 0; c < 4; c++) {
          const half8 af = *(const half8*)&h1_s[rb + c * 32 + quad * 8];
#pragma unroll
          for (int nt = 0; nt < 3; nt++)
            acc2[mi][nt] = __builtin_amdgcn_mfma_f32_16x16x32_f16(af, bc2[c][nt], acc2[mi][nt], 0, 0, 0);
        }
      }
    }

    // ---- pool in regs, stage to h2_s, write emb ----
    {
      int mi = 0;
      for (int mt = wave; mt < 9; mt += 4, mi++) {
        const int ppC = mt * 4 + quad;
#pragma unroll
        for (int nt = 0; nt < 3; nt++) {
          const int oc = nt * 16 + l15;
          float v = fmaxf(fmaxf(acc2[mi][nt][0], acc2[mi][nt][1]),
                          fmaxf(acc2[mi][nt][2], acc2[mi][nt][3])) + bia2[nt];
          v = fmaxf(v, 0.f);
          h2s_write: h2_s[oc * 36 + ppC] = (_Float16)v;
        }
      }
    }
    __syncthreads();   // epilogue staged (LDS drain only); also all h1/x reads done
    if (tid < 216) {
      half8* dst = (half8*)(emb + (size_t)(n0 + i) * 1728);
      dst[tid] = ((const half8*)h2_s)[tid];
    }
  }
}

// ---------------------------------------------------------------------------
// fp16-A x fp32-B MFMA GEMM: C[m,n] = act( sum_k A[m,k]*B[n,k] + bias[n] )
// BM=64, BN=32, BK=64, 256 threads. Single-barrier ping-pong K-loop:
// store staged regs -> LDS[buf]; sync; prefetch next tile -> regs (drained
// only at NEXT iteration's sync, after the MFMA phase); MFMA from LDS[buf].
// B is fp32 in global, converted to fp16 during staging (no cast pass).
// ---------------------------------------------------------------------------
template <int ACT>
__launch_bounds__(256, 4)
__global__ void gemm_h(const _Float16* __restrict__ A, const float* __restrict__ Bf,
                       const float* __restrict__ bias, _Float16* __restrict__ C,
                       int K, int lda, int ldb, int ldc) {
  __shared__ __align__(16) _Float16 As[2][64 * 72];
  __shared__ __align__(16) _Float16 Bs[2][32 * 72];
  const int tid = threadIdx.x;
  const int m0 = blockIdx.y * 64, n0 = blockIdx.x * 32;
  const int lane = tid & 63, wave = tid >> 6;
  const int quad = lane >> 4, l15 = lane & 15;
  const int wm = (wave >> 1) * 32, wn = (wave & 1) * 16;
  const int arow = tid >> 2, acol = (tid & 3) * 16;   // 64 rows x 16 halves
  const int brow = tid >> 3, bcol = (tid & 7) * 8;    // 32 rows x 8 floats

  const _Float16* Ap = A + (size_t)(m0 + arow) * lda + acol;
  const float* Bp = Bf + (size_t)(n0 + brow) * ldb + bcol;

  half8 av0 = *(const half8*)(Ap);
  half8 av1 = *(const half8*)(Ap + 8);
  floatx4 bv0 = *(const floatx4*)(Bp);
  floatx4 bv1 = *(const floatx4*)(Bp + 4);

  floatx4 acc[2];
#pragma unroll
  for (int a = 0; a < 2; a++)
#pragma unroll
    for (int r = 0; r < 4; r++) acc[a][r] = 0.f;

  int buf = 0;
  for (int k0 = 0; k0 < K; k0 += 64) {
    *(half8*)&As[buf][arow * 72 + acol] = av0;
    *(half8*)&As[buf][arow * 72 + acol + 8] = av1;
    {
      half8 bh;
      bh[0] = (_Float16)bv0[0]; bh[1] = (_Float16)bv0[1];
      bh[2] = (_Float16)bv0[2]; bh[3] = (_Float16)bv0[3];
      bh[4] = (_Float16)bv1[0]; bh[5] = (_Float16)bv1[1];
      bh[6] = (_Float16)bv1[2]; bh[7] = (_Float16)bv1[3];
      *(half8*)&Bs[buf][brow * 72 + bcol] = bh;
    }
    __syncthreads();
    if (k0 + 64 < K) {
      av0 = *(const half8*)(Ap + k0 + 64);
      av1 = *(const half8*)(Ap + k0 + 64 + 8);
      bv0 = *(const floatx4*)(Bp + k0 + 64);
      bv1 = *(const floatx4*)(Bp + k0 + 64 + 4);
    }
#pragma unroll
    for (int ks = 0; ks < 64; ks += 32) {
      const half8 af0 = *(const half8*)&As[buf][(wm + l15) * 72 + ks + quad * 8];
      const half8 af1 = *(const half8*)&As[buf][(wm + 16 + l15) * 72 + ks + quad * 8];
      const half8 bf0 = *(const half8*)&Bs[buf][(wn + l15) * 72 + ks + quad * 8];
      acc[0] = __builtin_amdgcn_mfma_f32_16x16x32_f16(af0, bf0, acc[0], 0, 0, 0);
      acc[1] = __builtin_amdgcn_mfma_f32_16x16x32_f16(af1, bf0, acc[1], 0, 0, 0);
    }
    buf ^= 1;
  }

  const int col = n0 + wn + l15;
  const float bcolv = bias[col];
#pragma unroll
  for (int mt = 0; mt < 2; mt++) {
#pragma unroll
    for (int r = 0; r < 4; r++) {
      const int row = m0 + wm + mt * 16 + quad * 4 + r;
      float v = acc[mt][r] + bcolv;
      if (ACT == 1) v = fmaxf(v, 0.f);
      if (ACT == 2) v = tanhf(v);
      C[(size_t)row * ldc + col] = (_Float16)v;
    }
  }
}

// ---------------------------------------------------------------------------
// Neighborhood attention: one wave per instance. <=8 grid neighbors.
// ---------------------------------------------------------------------------
__launch_bounds__(256)
__global__ void nbhd_k(_Float16* __restrict__ H2, const _Float16* __restrict__ T) {
  const int wid = (blockIdx.x * 256 + threadIdx.x) >> 6;
  const int lane = threadIdx.x & 63;
  const int r = wid >> 6, c = wid & 63;
  const _Float16* hi = H2 + (size_t)wid * 1024;
  float hreg[8];
#pragma unroll
  for (int u = 0; u < 8; u++) hreg[u] = (float)hi[u * 64 + lane];

  float sv[8];
  int jv[8];
  bool ok[8];
  int q = 0;
#pragma unroll
  for (int dr = -1; dr <= 1; dr++)
#pragma unroll
    for (int dc = -1; dc <= 1; dc++) {
      if (dr == 0 && dc == 0) continue;
      const int rr = r + dr, cc = c + dc;
      const bool v = (rr >= 0) && (rr < 64) && (cc >= 0) && (cc < 64);
      const int j = v ? (rr * 64 + cc) : wid;
      const _Float16* tj = T + (size_t)j * 512;
      float s = 0.f;
#pragma unroll
      for (int u = 0; u < 8; u++) s = fmaf(hreg[u], (float)tj[u * 64 + lane], s);
#pragma unroll
      for (int off = 32; off > 0; off >>= 1) s += __shfl_xor(s, off, 64);
      sv[q] = v ? s : -3.4e38f;
      jv[q] = j;
      ok[q] = v;
      q++;
    }

  float m = sv[0];
#pragma unroll
  for (int a = 1; a < 8; a++) m = fmaxf(m, sv[a]);
  float e[8], den = 0.f;
#pragma unroll
  for (int a = 0; a < 8; a++) {
    e[a] = ok[a] ? expf(sv[a] - m) : 0.f;
    den += e[a];
  }
  const float inv = 1.f / den;

  float outv[8];
#pragma unroll
  for (int u = 0; u < 8; u++) outv[u] = 0.f;
#pragma unroll
  for (int a = 0; a < 8; a++) {
    const float al = e[a] * inv;
    const _Float16* hj = H2 + (size_t)jv[a] * 1024;
#pragma unroll
    for (int u = 0; u < 8; u++) outv[u] = fmaf(al, (float)hj[u * 64 + lane], outv[u]);
  }
  _Float16* dst = H2 + (size_t)wid * 1024 + 512;
#pragma unroll
  for (int u = 0; u < 8; u++) dst[u * 64 + lane] = (_Float16)outv[u];
}

// ---------------------------------------------------------------------------
// tl[t,n] = P[n,:] . templates[t,:]
// ---------------------------------------------------------------------------
__launch_bounds__(256)
__global__ void templ_scores(const _Float16* __restrict__ P, const float* __restrict__ tmpl,
                             float* __restrict__ tl) {
  const int wid = (blockIdx.x * 256 + threadIdx.x) >> 6;
  const int lane = threadIdx.x & 63;
  const _Float16* p = P + (size_t)wid * 1024;
  float pr[16];
#pragma unroll
  for (int u = 0; u < 16; u++) pr[u] = (float)p[u * 64 + lane];
  for (int t = 0; t < 10; t++) {
    const float* tp = tmpl + t * 1024;
    float s = 0.f;
#pragma unroll
    for (int u = 0; u < 16; u++) s = fmaf(pr[u], tp[u * 64 + lane], s);
#pragma unroll
    for (int off = 32; off > 0; off >>= 1) s += __shfl_xor(s, off, 64);
    if (lane == 0) tl[t * NINST + wid] = s;
  }
}

// ---------------------------------------------------------------------------
// Per-template softmax over N=4096; also zeros embs rows (for embs_k atomics)
// ---------------------------------------------------------------------------
__launch_bounds__(256)
__global__ void softmax_rows(const float* __restrict__ tl, float* __restrict__ betas,
                             float* __restrict__ embs) {
  const int t = blockIdx.x, tid = threadIdx.x;
  __shared__ float red[256];
  for (int i = tid; i < 1024; i += 256) embs[t * 1024 + i] = 0.f;
  const float* row = tl + t * NINST;
  float m = -3.4e38f;
  for (int i = tid; i < NINST; i += 256) m = fmaxf(m, row[i]);
  red[tid] = m;
  __syncthreads();
  for (int s = 128; s > 0; s >>= 1) {
    if (tid < s) red[tid] = fmaxf(red[tid], red[tid + s]);
    __syncthreads();
  }
  m = red[0];
  __syncthreads();
  float sum = 0.f;
  for (int i = tid; i < NINST; i += 256) sum += expf(row[i] - m);
  red[tid] = sum;
  __syncthreads();
  for (int s = 128; s > 0; s >>= 1) {
    if (tid < s) red[tid] += red[tid + s];
    __syncthreads();
  }
  const float inv = 1.f / red[0];
  for (int i = tid; i < NINST; i += 256) betas[t * NINST + i] = expf(row[i] - m) * inv;
}

// ---------------------------------------------------------------------------
// embs[t,k] += sum_{n in slice} betas[t,n] * H2h[n,k]
// ---------------------------------------------------------------------------
__launch_bounds__(256)
__global__ void embs_k(const float* __restrict__ betas, const _Float16* __restrict__ H2,
                       float* __restrict__ embs) {
  const int k = blockIdx.x * 256 + threadIdx.x;
  const int nbase = blockIdx.y * 256;
  float acc[10];
#pragma unroll
  for (int t = 0; t < 10; t++) acc[t] = 0.f;
  for (int n = nbase; n < nbase + 256; n++) {
    const float v = (float)H2[(size_t)n * 1024 + k];
#pragma unroll
    for (int t = 0; t < 10; t++) acc[t] = fmaf(betas[t * NINST + n], v, acc[t]);
  }
#pragma unroll
  for (int t = 0; t < 10; t++) atomicAdd(&embs[t * 1024 + k], acc[t]);
}

// ---------------------------------------------------------------------------
// Global attention tail
// ---------------------------------------------------------------------------
__launch_bounds__(256)
__global__ void ga_k(const float* __restrict__ embs_g, const float* __restrict__ ga1_w,
                     const float* __restrict__ ga1_b, const float* __restrict__ ga2_w,
                     const float* __restrict__ ga2_b, const float* __restrict__ cls_w,
                     const float* __restrict__ cls_b, float* __restrict__ out,
                     float* __restrict__ gammas_ws) {
  __shared__ __align__(16) float embs_s[10 * 1024];
  __shared__ float hh[10 * 128];
  __shared__ float red[256];
  __shared__ float g_s[10], gam_s[10];
  __shared__ float M_s[1024];
  const int tid = threadIdx.x;
  const int wave = tid >> 6, lane = tid & 63;

  for (int i = tid; i < 10240; i += 256) embs_s[i] = embs_g[i];
  __syncthreads();

  for (int j = 0; j < 32; j++) {
    const int d = wave * 32 + j;
    float wreg[16];
#pragma unroll
    for (int u = 0; u < 16; u++) wreg[u] = ga1_w[(size_t)d * 1024 + u * 64 + lane];
    const float bd = ga1_b[d];
    for (int t = 0; t < 10; t++) {
      float s = 0.f;
#pragma unroll
      for (int u = 0; u < 16; u++) s = fmaf(wreg[u], embs_s[t * 1024 + u * 64 + lane], s);
#pragma unroll
      for (int off = 32; off > 0; off >>= 1) s += __shfl_xor(s, off, 64);
      if (lane == 0) hh[t * 128 + d] = tanhf(s + bd);
    }
  }
  __syncthreads();

  if (wave == 0) {
    for (int t = 0; t < 10; t++) {
      float s = hh[t * 128 + lane] * ga2_w[lane] + hh[t * 128 + 64 + lane] * ga2_w[64 + lane];
#pragma unroll
      for (int off = 32; off > 0; off >>= 1) s += __shfl_xor(s, off, 64);
      if (lane == 0) g_s[t] = s + ga2_b[0];
    }
  }
  __syncthreads();

  if (tid == 0) {
    float m = g_s[0];
    for (int t = 1; t < 10; t++) m = fmaxf(m, g_s[t]);
    float sum = 0.f;
    for (int t = 0; t < 10; t++) sum += expf(g_s[t] - m);
    for (int t = 0; t < 10; t++) {
      gam_s[t] = expf(g_s[t] - m) / sum;
      gammas_ws[t] = gam_s[t];
    }
  }
  __syncthreads();

  for (int k = tid; k < 1024; k += 256) {
    float a = 0.f;
#pragma unroll
    for (int t = 0; t < 10; t++) a = fmaf(gam_s[t], embs_s[t * 1024 + k], a);
    M_s[k] = a;
  }
  __syncthreads();

  float part = 0.f;
  for (int k = tid; k < 1024; k += 256) part = fmaf(M_s[k], cls_w[k], part);
  red[tid] = part;
  __syncthreads();
  for (int s = 128; s > 0; s >>= 1) {
    if (tid < s) red[tid] += red[tid + s];
    __syncthreads();
  }
  if (tid == 0) {
    const float z = red[0] + cls_b[0];
    const float yp = 1.f / (1.f + expf(-z));
    out[0] = yp;
    out[1] = (yp >= 0.5f) ? 1.f : 0.f;
  }
}

// ---------------------------------------------------------------------------
// A[n] = sum_t gammas[t] * betas[t,n]
// ---------------------------------------------------------------------------
__launch_bounds__(256)
__global__ void a_k(const float* __restrict__ betas, const float* __restrict__ gam,
                    float* __restrict__ outA) {
  const int n = blockIdx.x * 256 + threadIdx.x;
  float a = 0.f;
#pragma unroll
  for (int t = 0; t < 10; t++) a = fmaf(gam[t], betas[t * NINST + n], a);
  outA[n] = a;
}

// ---------------------------------------------------------------------------
extern "C" void kernel_launch(void* const* d_in, const int* in_sizes, int n_in,
                              void* d_out, int out_size, void* d_ws, size_t ws_size,
                              hipStream_t stream) {
  const float* x       = (const float*)d_in[0];
  const float* w1      = (const float*)d_in[2];
  const float* b1      = (const float*)d_in[3];
  const float* w2      = (const float*)d_in[4];
  const float* b2      = (const float*)d_in[5];
  const float* fc1_w   = (const float*)d_in[6];
  const float* fc1_b   = (const float*)d_in[7];
  const float* fc2_w   = (const float*)d_in[8];
  const float* fc2_b   = (const float*)d_in[9];
  const float* nbr_w   = (const float*)d_in[10];
  const float* nbr_b   = (const float*)d_in[11];
  const float* tmpl    = (const float*)d_in[12];
  const float* proto_w = (const float*)d_in[13];
  const float* proto_b = (const float*)d_in[14];
  const float* ga1_w   = (const float*)d_in[15];
  const float* ga1_b   = (const float*)d_in[16];
  const float* ga2_w   = (const float*)d_in[17];
  const float* ga2_b   = (const float*)d_in[18];
  const float* cls_w   = (const float*)d_in[19];
  const float* cls_b   = (const float*)d_in[20];
  float* out = (float*)d_out;

  char* w = (char*)d_ws;
  _Float16* embh = (_Float16*)w;  w += (size_t)4096 * 1728 * 2;
  _Float16* H1h  = (_Float16*)w;  w += (size_t)4096 * 512 * 2;
  _Float16* H2h  = (_Float16*)w;  w += (size_t)4096 * 1024 * 2;
  _Float16* TbH  = (_Float16*)w;  w += (size_t)4096 * 512 * 2;
  _Float16* PH   = (_Float16*)w;  w += (size_t)4096 * 1024 * 2;
  _Float16* w1tG = (_Float16*)w;  w += (size_t)48 * 64 * 2;
  _Float16* w2tG = (_Float16*)w;  w += (size_t)3 * 48 * 128 * 2;
  float* tl   = (float*)w;        w += (size_t)10 * NINST * 4;
  float* bet  = (float*)w;        w += (size_t)10 * NINST * 4;
  float* embs = (float*)w;        w += (size_t)10 * 1024 * 4;
  float* gam  = (float*)w;        w += 256;

  xform_w12<<<64, 256, 0, stream>>>(w1, w2, w1tG, w2tG);
  conv_fused<<<NINST / 4, 256, 0, stream>>>(x, w1tG, w2tG, b1, b2, embh);

  gemm_h<1><<<dim3(16, 64), 256, 0, stream>>>(embh, fc1_w, fc1_b, H1h, 1728, 1728, 1728, 512);
  gemm_h<1><<<dim3(16, 64), 256, 0, stream>>>(H1h, fc2_w, fc2_b, H2h, 512, 512, 512, 1024);
  gemm_h<2><<<dim3(16, 64), 256, 0, stream>>>(H2h, nbr_w, nbr_b, TbH, 512, 1024, 512, 512);
  nbhd_k<<<1024, 256, 0, stream>>>(H2h, TbH);
  gemm_h<2><<<dim3(32, 64), 256, 0, stream>>>(H2h, proto_w, proto_b, PH, 1024, 1024, 1024, 1024);
  templ_scores<<<1024, 256, 0, stream>>>(PH, tmpl, tl);
  softmax_rows<<<10, 256, 0, stream>>>(tl, bet, embs);
  embs_k<<<dim3(4, 16), 256, 0, stream>>>(bet, H2h, embs);
  ga_k<<<1, 256, 0, stream>>>(embs, ga1_w, ga1_b, ga2_w, ga2_b, cls_w, cls_b, out, gam);
  a_k<<<16, 256, 0, stream>>>(bet, gam, out + 2);
}

// Round 8
// 558.883 us; speedup vs baseline: 1.2581x; 1.2581x over previous
//
#include <hip/hip_runtime.h>
#include <math.h>

#define NINST 4096

typedef _Float16 half8 __attribute__((ext_vector_type(8)));
typedef _Float16 half4 __attribute__((ext_vector_type(4)));
typedef float floatx4 __attribute__((ext_vector_type(4)));

// ---------------------------------------------------------------------------
// xform_w12: w1 (36,3,4,4) -> w1t [48 oc][64], k = ky*16+kx*4+ic
//            w2 (48,36,3,3) -> w2t [3 ky][48 oc][128], k = kx*40+ic (k<120)
// zero-padded elsewhere. 64 blocks (grid-stride).
// ---------------------------------------------------------------------------
__global__ void xform_w12(const float* __restrict__ w1, const float* __restrict__ w2,
                          _Float16* __restrict__ w1t, _Float16* __restrict__ w2t) {
  for (int i = blockIdx.x * 256 + threadIdx.x; i < 48 * 64; i += gridDim.x * 256) {
    const int oc = i >> 6, k = i & 63;
    const int ky = k >> 4, r = k & 15, kx = r >> 2, ic = r & 3;
    float v = 0.f;
    if (oc < 36 && ic < 3) v = w1[((oc * 3 + ic) * 4 + ky) * 4 + kx];
    w1t[i] = (_Float16)v;
  }
  for (int i = blockIdx.x * 256 + threadIdx.x; i < 3 * 48 * 128; i += gridDim.x * 256) {
    const int ky = i / 6144, r = i % 6144;
    const int oc = r >> 7, k = r & 127;
    float v = 0.f;
    if (k < 120) {
      const int kx = k / 40, ic = k % 40;
      if (ic < 36) v = w2[((oc * 36 + ic) * 3 + ky) * 3 + kx];
    }
    w2t[i] = (_Float16)v;
  }
}

// ---------------------------------------------------------------------------
// MFMA conv, one block per instance. __launch_bounds__(256,2) gives the
// allocator 256 VGPRs so the hoisted weight fragments (6 conv1 + 12/ky conv2
// half8 = up to ~72 VGPRs live) STAY in registers across the mt loops —
// at a 128-VGPR cap the compiler sinks these loads into the loop and every
// MFMA pays ~250-cycle L2 latency (the r5-r7 ~200 us plateau).
// LDS: x_s 8KB + h1_s 15.4KB + h2_s 3.4KB = 26.8KB. 3 barriers per block.
// Pool-aligned m-map: m = window*4 + (dy*2+dx) -> C-quad regs = 2x2 window.
// ---------------------------------------------------------------------------
__launch_bounds__(256, 2)
__global__ void conv_fused(const float* __restrict__ x,
                           const _Float16* __restrict__ w1t_g,
                           const _Float16* __restrict__ w2t_g,
                           const float* __restrict__ b1, const float* __restrict__ b2,
                           _Float16* __restrict__ emb) {
  __shared__ __align__(16) _Float16 x_s[4096];      // [1024 pix][4 ch]
  __shared__ __align__(16) _Float16 h1_s[7856];     // [196 pix][40 ic] + 16 pad
  __shared__ __align__(16) _Float16 h2_s[1728];     // epilogue staging

  const int n = blockIdx.x, tid = threadIdx.x;
  const int lane = tid & 63, wave = tid >> 6;
  const int quad = lane >> 4, l15 = lane & 15;

  // ---- stage x: fp32 NCHW (nontemporal) -> fp16 channel-last [1024][4] ----
  {
    const float* xb = x + (size_t)n * 3072 + tid * 4;
    floatx4 xr0 = __builtin_nontemporal_load((const floatx4*)(xb));
    floatx4 xr1 = __builtin_nontemporal_load((const floatx4*)(xb + 1024));
    floatx4 xr2 = __builtin_nontemporal_load((const floatx4*)(xb + 2048));
    half8 pk0, pk1;
    pk0[0] = (_Float16)xr0[0]; pk0[1] = (_Float16)xr1[0]; pk0[2] = (_Float16)xr2[0]; pk0[3] = (_Float16)0.f;
    pk0[4] = (_Float16)xr0[1]; pk0[5] = (_Float16)xr1[1]; pk0[6] = (_Float16)xr2[1]; pk0[7] = (_Float16)0.f;
    pk1[0] = (_Float16)xr0[2]; pk1[1] = (_Float16)xr1[2]; pk1[2] = (_Float16)xr2[2]; pk1[3] = (_Float16)0.f;
    pk1[4] = (_Float16)xr0[3]; pk1[5] = (_Float16)xr1[3]; pk1[6] = (_Float16)xr2[3]; pk1[7] = (_Float16)0.f;
    *(half8*)&x_s[tid * 16] = pk0;
    *(half8*)&x_s[tid * 16 + 8] = pk1;
    if (tid < 16) h1_s[7840 + tid] = (_Float16)0.f;  // zero overrun pad
  }
  __syncthreads();

  // ---- conv1: M=784, N=48(36), K=64(48) -> h1 pooled+relu ----
  {
    half8 bc[2][3];
#pragma unroll
    for (int c = 0; c < 2; c++)
#pragma unroll
      for (int nt = 0; nt < 3; nt++)
        bc[c][nt] = *(const half8*)&w1t_g[(nt * 16 + l15) * 64 + c * 32 + quad * 8];
    float bia[3];
#pragma unroll
    for (int nt = 0; nt < 3; nt++) {
      const int oc = nt * 16 + l15;
      bia[nt] = (oc < 36) ? b1[oc] : 0.f;
    }
    for (int mt = wave; mt < 49; mt += 4) {
      const int mA = mt * 16 + l15;
      const int ppA = mA >> 2, dA = mA & 3;
      const int yA = 2 * (ppA / 14) + (dA >> 1);
      const int xA = 2 * (ppA % 14) + (dA & 1);
      floatx4 a1[3];
#pragma unroll
      for (int nt = 0; nt < 3; nt++)
#pragma unroll
        for (int r = 0; r < 4; r++) a1[nt][r] = 0.f;
#pragma unroll
      for (int c = 0; c < 2; c++) {
        const int row = yA + c * 2 + (quad >> 1);
        const half8 af = *(const half8*)&x_s[row * 128 + xA * 4 + (quad & 1) * 8];
#pragma unroll
        for (int nt = 0; nt < 3; nt++)
          a1[nt] = __builtin_amdgcn_mfma_f32_16x16x32_f16(af, bc[c][nt], a1[nt], 0, 0, 0);
      }
      const int ppC = mt * 4 + quad;
#pragma unroll
      for (int nt = 0; nt < 3; nt++) {
        const int oc = nt * 16 + l15;
        float v = fmaxf(fmaxf(a1[nt][0], a1[nt][1]), fmaxf(a1[nt][2], a1[nt][3])) + bia[nt];
        v = fmaxf(v, 0.f);
        if (oc < 40) h1_s[ppC * 40 + oc] = (_Float16)v;  // oc 36..39 write pad zeros
      }
    }
  }
  __syncthreads();   // h1 ready

  // ---- conv2: M=144, N=48, K=3ky x 128(120) ----
  floatx4 acc2[3][3];
#pragma unroll
  for (int a = 0; a < 3; a++)
#pragma unroll
    for (int j = 0; j < 3; j++)
#pragma unroll
      for (int r = 0; r < 4; r++) acc2[a][j][r] = 0.f;

  for (int ky = 0; ky < 3; ky++) {
    half8 bc2[4][3];
#pragma unroll
    for (int c = 0; c < 4; c++)
#pragma unroll
      for (int nt = 0; nt < 3; nt++)
        bc2[c][nt] = *(const half8*)&w2t_g[ky * 6144 + (nt * 16 + l15) * 128 + c * 32 + quad * 8];
    int mi = 0;
    for (int mt = wave; mt < 9; mt += 4, mi++) {
      const int mA = mt * 16 + l15;
      const int ppA = mA >> 2, dA = mA & 3;
      const int y2 = 2 * (ppA / 6) + (dA >> 1);
      const int x2 = 2 * (ppA % 6) + (dA & 1);
      const int rb = ((y2 + ky) * 14 + x2) * 40;
#pragma unroll
      for (int c = 0; c < 4; c++) {
        const half8 af = *(const half8*)&h1_s[rb + c * 32 + quad * 8];
#pragma unroll
        for (int nt = 0; nt < 3; nt++)
          acc2[mi][nt] = __builtin_amdgcn_mfma_f32_16x16x32_f16(af, bc2[c][nt], acc2[mi][nt], 0, 0, 0);
      }
    }
  }

  // ---- pool in regs, stage to h2_s, write emb ----
  {
    float bia2[3];
#pragma unroll
    for (int nt = 0; nt < 3; nt++) bia2[nt] = b2[nt * 16 + l15];
    int mi = 0;
    for (int mt = wave; mt < 9; mt += 4, mi++) {
      const int ppC = mt * 4 + quad;
#pragma unroll
      for (int nt = 0; nt < 3; nt++) {
        const int oc = nt * 16 + l15;
        float v = fmaxf(fmaxf(acc2[mi][nt][0], acc2[mi][nt][1]),
                        fmaxf(acc2[mi][nt][2], acc2[mi][nt][3])) + bia2[nt];
        v = fmaxf(v, 0.f);
        h2_s[oc * 36 + ppC] = (_Float16)v;
      }
    }
  }
  __syncthreads();   // epilogue staged (LDS drain only)
  if (tid < 216) {
    half8* dst = (half8*)(emb + (size_t)n * 1728);
    dst[tid] = ((const half8*)h2_s)[tid];
  }
}

// ---------------------------------------------------------------------------
// fp16-A x fp32-B MFMA GEMM: C[m,n] = act( sum_k A[m,k]*B[n,k] + bias[n] )
// BM=64, BN=32, BK=64, 256 threads. Single-barrier ping-pong K-loop; B fp32
// in global, converted to fp16 during staging (no separate cast pass).
// ACT: 0=none 1=relu 2=tanh.
// ---------------------------------------------------------------------------
template <int ACT>
__launch_bounds__(256, 4)
__global__ void gemm_h(const _Float16* __restrict__ A, const float* __restrict__ Bf,
                       const float* __restrict__ bias, _Float16* __restrict__ C,
                       int K, int lda, int ldb, int ldc) {
  __shared__ __align__(16) _Float16 As[2][64 * 72];
  __shared__ __align__(16) _Float16 Bs[2][32 * 72];
  const int tid = threadIdx.x;
  const int m0 = blockIdx.y * 64, n0 = blockIdx.x * 32;
  const int lane = tid & 63, wave = tid >> 6;
  const int quad = lane >> 4, l15 = lane & 15;
  const int wm = (wave >> 1) * 32, wn = (wave & 1) * 16;
  const int arow = tid >> 2, acol = (tid & 3) * 16;   // 64 rows x 16 halves
  const int brow = tid >> 3, bcol = (tid & 7) * 8;    // 32 rows x 8 floats

  const _Float16* Ap = A + (size_t)(m0 + arow) * lda + acol;
  const float* Bp = Bf + (size_t)(n0 + brow) * ldb + bcol;

  half8 av0 = *(const half8*)(Ap);
  half8 av1 = *(const half8*)(Ap + 8);
  floatx4 bv0 = *(const floatx4*)(Bp);
  floatx4 bv1 = *(const floatx4*)(Bp + 4);

  floatx4 acc[2];
#pragma unroll
  for (int a = 0; a < 2; a++)
#pragma unroll
    for (int r = 0; r < 4; r++) acc[a][r] = 0.f;

  int buf = 0;
  for (int k0 = 0; k0 < K; k0 += 64) {
    *(half8*)&As[buf][arow * 72 + acol] = av0;
    *(half8*)&As[buf][arow * 72 + acol + 8] = av1;
    {
      half8 bh;
      bh[0] = (_Float16)bv0[0]; bh[1] = (_Float16)bv0[1];
      bh[2] = (_Float16)bv0[2]; bh[3] = (_Float16)bv0[3];
      bh[4] = (_Float16)bv1[0]; bh[5] = (_Float16)bv1[1];
      bh[6] = (_Float16)bv1[2]; bh[7] = (_Float16)bv1[3];
      *(half8*)&Bs[buf][brow * 72 + bcol] = bh;
    }
    __syncthreads();
    if (k0 + 64 < K) {
      av0 = *(const half8*)(Ap + k0 + 64);
      av1 = *(const half8*)(Ap + k0 + 64 + 8);
      bv0 = *(const floatx4*)(Bp + k0 + 64);
      bv1 = *(const floatx4*)(Bp + k0 + 64 + 4);
    }
#pragma unroll
    for (int ks = 0; ks < 64; ks += 32) {
      const half8 af0 = *(const half8*)&As[buf][(wm + l15) * 72 + ks + quad * 8];
      const half8 af1 = *(const half8*)&As[buf][(wm + 16 + l15) * 72 + ks + quad * 8];
      const half8 bf0 = *(const half8*)&Bs[buf][(wn + l15) * 72 + ks + quad * 8];
      acc[0] = __builtin_amdgcn_mfma_f32_16x16x32_f16(af0, bf0, acc[0], 0, 0, 0);
      acc[1] = __builtin_amdgcn_mfma_f32_16x16x32_f16(af1, bf0, acc[1], 0, 0, 0);
    }
    buf ^= 1;
  }

  const int col = n0 + wn + l15;
  const float bcolv = bias[col];
#pragma unroll
  for (int mt = 0; mt < 2; mt++) {
#pragma unroll
    for (int r = 0; r < 4; r++) {
      const int row = m0 + wm + mt * 16 + quad * 4 + r;
      float v = acc[mt][r] + bcolv;
      if (ACT == 1) v = fmaxf(v, 0.f);
      if (ACT == 2) v = tanhf(v);
      C[(size_t)row * ldc + col] = (_Float16)v;
    }
  }
}

// ---------------------------------------------------------------------------
// Neighborhood attention: one wave per instance. <=8 grid neighbors.
// ---------------------------------------------------------------------------
__launch_bounds__(256)
__global__ void nbhd_k(_Float16* __restrict__ H2, const _Float16* __restrict__ T) {
  const int wid = (blockIdx.x * 256 + threadIdx.x) >> 6;
  const int lane = threadIdx.x & 63;
  const int r = wid >> 6, c = wid & 63;
  const _Float16* hi = H2 + (size_t)wid * 1024;
  float hreg[8];
#pragma unroll
  for (int u = 0; u < 8; u++) hreg[u] = (float)hi[u * 64 + lane];

  float sv[8];
  int jv[8];
  bool ok[8];
  int q = 0;
#pragma unroll
  for (int dr = -1; dr <= 1; dr++)
#pragma unroll
    for (int dc = -1; dc <= 1; dc++) {
      if (dr == 0 && dc == 0) continue;
      const int rr = r + dr, cc = c + dc;
      const bool v = (rr >= 0) && (rr < 64) && (cc >= 0) && (cc < 64);
      const int j = v ? (rr * 64 + cc) : wid;
      const _Float16* tj = T + (size_t)j * 512;
      float s = 0.f;
#pragma unroll
      for (int u = 0; u < 8; u++) s = fmaf(hreg[u], (float)tj[u * 64 + lane], s);
#pragma unroll
      for (int off = 32; off > 0; off >>= 1) s += __shfl_xor(s, off, 64);
      sv[q] = v ? s : -3.4e38f;
      jv[q] = j;
      ok[q] = v;
      q++;
    }

  float m = sv[0];
#pragma unroll
  for (int a = 1; a < 8; a++) m = fmaxf(m, sv[a]);
  float e[8], den = 0.f;
#pragma unroll
  for (int a = 0; a < 8; a++) {
    e[a] = ok[a] ? expf(sv[a] - m) : 0.f;
    den += e[a];
  }
  const float inv = 1.f / den;

  float outv[8];
#pragma unroll
  for (int u = 0; u < 8; u++) outv[u] = 0.f;
#pragma unroll
  for (int a = 0; a < 8; a++) {
    const float al = e[a] * inv;
    const _Float16* hj = H2 + (size_t)jv[a] * 1024;
#pragma unroll
    for (int u = 0; u < 8; u++) outv[u] = fmaf(al, (float)hj[u * 64 + lane], outv[u]);
  }
  _Float16* dst = H2 + (size_t)wid * 1024 + 512;
#pragma unroll
  for (int u = 0; u < 8; u++) dst[u * 64 + lane] = (_Float16)outv[u];
}

// ---------------------------------------------------------------------------
// tl[t,n] = P[n,:] . templates[t,:]
// ---------------------------------------------------------------------------
__launch_bounds__(256)
__global__ void templ_scores(const _Float16* __restrict__ P, const float* __restrict__ tmpl,
                             float* __restrict__ tl) {
  const int wid = (blockIdx.x * 256 + threadIdx.x) >> 6;
  const int lane = threadIdx.x & 63;
  const _Float16* p = P + (size_t)wid * 1024;
  float pr[16];
#pragma unroll
  for (int u = 0; u < 16; u++) pr[u] = (float)p[u * 64 + lane];
  for (int t = 0; t < 10; t++) {
    const float* tp = tmpl + t * 1024;
    float s = 0.f;
#pragma unroll
    for (int u = 0; u < 16; u++) s = fmaf(pr[u], tp[u * 64 + lane], s);
#pragma unroll
    for (int off = 32; off > 0; off >>= 1) s += __shfl_xor(s, off, 64);
    if (lane == 0) tl[t * NINST + wid] = s;
  }
}

// ---------------------------------------------------------------------------
// Per-template softmax over N=4096; also zeros embs rows (for embs_k atomics)
// ---------------------------------------------------------------------------
__launch_bounds__(256)
__global__ void softmax_rows(const float* __restrict__ tl, float* __restrict__ betas,
                             float* __restrict__ embs) {
  const int t = blockIdx.x, tid = threadIdx.x;
  __shared__ float red[256];
  for (int i = tid; i < 1024; i += 256) embs[t * 1024 + i] = 0.f;
  const float* row = tl + t * NINST;
  float m = -3.4e38f;
  for (int i = tid; i < NINST; i += 256) m = fmaxf(m, row[i]);
  red[tid] = m;
  __syncthreads();
  for (int s = 128; s > 0; s >>= 1) {
    if (tid < s) red[tid] = fmaxf(red[tid], red[tid + s]);
    __syncthreads();
  }
  m = red[0];
  __syncthreads();
  float sum = 0.f;
  for (int i = tid; i < NINST; i += 256) sum += expf(row[i] - m);
  red[tid] = sum;
  __syncthreads();
  for (int s = 128; s > 0; s >>= 1) {
    if (tid < s) red[tid] += red[tid + s];
    __syncthreads();
  }
  const float inv = 1.f / red[0];
  for (int i = tid; i < NINST; i += 256) betas[t * NINST + i] = expf(row[i] - m) * inv;
}

// ---------------------------------------------------------------------------
// embs[t,k] += sum_{n in slice} betas[t,n] * H2h[n,k]
// ---------------------------------------------------------------------------
__launch_bounds__(256)
__global__ void embs_k(const float* __restrict__ betas, const _Float16* __restrict__ H2,
                       float* __restrict__ embs) {
  const int k = blockIdx.x * 256 + threadIdx.x;
  const int nbase = blockIdx.y * 256;
  float acc[10];
#pragma unroll
  for (int t = 0; t < 10; t++) acc[t] = 0.f;
  for (int n = nbase; n < nbase + 256; n++) {
    const float v = (float)H2[(size_t)n * 1024 + k];
#pragma unroll
    for (int t = 0; t < 10; t++) acc[t] = fmaf(betas[t * NINST + n], v, acc[t]);
  }
#pragma unroll
  for (int t = 0; t < 10; t++) atomicAdd(&embs[t * 1024 + k], acc[t]);
}

// ---------------------------------------------------------------------------
// Global attention tail: g, gammas, M, Y_prob, Y_hat, and A (fused a_k).
// out[0]=Y_prob, out[1]=Y_hat, out[2..4098]=A. Single block.
// ---------------------------------------------------------------------------
__launch_bounds__(256)
__global__ void ga_k(const float* __restrict__ embs_g, const float* __restrict__ ga1_w,
                     const float* __restrict__ ga1_b, const float* __restrict__ ga2_w,
                     const float* __restrict__ ga2_b, const float* __restrict__ cls_w,
                     const float* __restrict__ cls_b, const float* __restrict__ betas,
                     float* __restrict__ out) {
  __shared__ __align__(16) float embs_s[10 * 1024];
  __shared__ float hh[10 * 128];
  __shared__ float red[256];
  __shared__ float g_s[10], gam_s[10];
  __shared__ float M_s[1024];
  const int tid = threadIdx.x;
  const int wave = tid >> 6, lane = tid & 63;

  for (int i = tid; i < 10240; i += 256) embs_s[i] = embs_g[i];
  __syncthreads();

  for (int j = 0; j < 32; j++) {
    const int d = wave * 32 + j;
    float wreg[16];
#pragma unroll
    for (int u = 0; u < 16; u++) wreg[u] = ga1_w[(size_t)d * 1024 + u * 64 + lane];
    const float bd = ga1_b[d];
    for (int t = 0; t < 10; t++) {
      float s = 0.f;
#pragma unroll
      for (int u = 0; u < 16; u++) s = fmaf(wreg[u], embs_s[t * 1024 + u * 64 + lane], s);
#pragma unroll
      for (int off = 32; off > 0; off >>= 1) s += __shfl_xor(s, off, 64);
      if (lane == 0) hh[t * 128 + d] = tanhf(s + bd);
    }
  }
  __syncthreads();

  if (wave == 0) {
    for (int t = 0; t < 10; t++) {
      float s = hh[t * 128 + lane] * ga2_w[lane] + hh[t * 128 + 64 + lane] * ga2_w[64 + lane];
#pragma unroll
      for (int off = 32; off > 0; off >>= 1) s += __shfl_xor(s, off, 64);
      if (lane == 0) g_s[t] = s + ga2_b[0];
    }
  }
  __syncthreads();

  if (tid == 0) {
    float m = g_s[0];
    for (int t = 1; t < 10; t++) m = fmaxf(m, g_s[t]);
    float sum = 0.f;
    for (int t = 0; t < 10; t++) sum += expf(g_s[t] - m);
    for (int t = 0; t < 10; t++) gam_s[t] = expf(g_s[t] - m) / sum;
  }
  __syncthreads();

  // A[n] = sum_t gam[t]*betas[t,n]   (fused former a_k)
  for (int nn = tid; nn < NINST; nn += 256) {
    float a = 0.f;
#pragma unroll
    for (int t = 0; t < 10; t++) a = fmaf(gam_s[t], betas[t * NINST + nn], a);
    out[2 + nn] = a;
  }

  for (int k = tid; k < 1024; k += 256) {
    float a = 0.f;
#pragma unroll
    for (int t = 0; t < 10; t++) a = fmaf(gam_s[t], embs_s[t * 1024 + k], a);
    M_s[k] = a;
  }
  __syncthreads();

  float part = 0.f;
  for (int k = tid; k < 1024; k += 256) part = fmaf(M_s[k], cls_w[k], part);
  red[tid] = part;
  __syncthreads();
  for (int s = 128; s > 0; s >>= 1) {
    if (tid < s) red[tid] += red[tid + s];
    __syncthreads();
  }
  if (tid == 0) {
    const float z = red[0] + cls_b[0];
    const float yp = 1.f / (1.f + expf(-z));
    out[0] = yp;
    out[1] = (yp >= 0.5f) ? 1.f : 0.f;
  }
}

// ---------------------------------------------------------------------------
extern "C" void kernel_launch(void* const* d_in, const int* in_sizes, int n_in,
                              void* d_out, int out_size, void* d_ws, size_t ws_size,
                              hipStream_t stream) {
  const float* x       = (const float*)d_in[0];
  const float* w1      = (const float*)d_in[2];
  const float* b1      = (const float*)d_in[3];
  const float* w2      = (const float*)d_in[4];
  const float* b2      = (const float*)d_in[5];
  const float* fc1_w   = (const float*)d_in[6];
  const float* fc1_b   = (const float*)d_in[7];
  const float* fc2_w   = (const float*)d_in[8];
  const float* fc2_b   = (const float*)d_in[9];
  const float* nbr_w   = (const float*)d_in[10];
  const float* nbr_b   = (const float*)d_in[11];
  const float* tmpl    = (const float*)d_in[12];
  const float* proto_w = (const float*)d_in[13];
  const float* proto_b = (const float*)d_in[14];
  const float* ga1_w   = (const float*)d_in[15];
  const float* ga1_b   = (const float*)d_in[16];
  const float* ga2_w   = (const float*)d_in[17];
  const float* ga2_b   = (const float*)d_in[18];
  const float* cls_w   = (const float*)d_in[19];
  const float* cls_b   = (const float*)d_in[20];
  float* out = (float*)d_out;

  char* w = (char*)d_ws;
  _Float16* embh = (_Float16*)w;  w += (size_t)4096 * 1728 * 2;
  _Float16* H1h  = (_Float16*)w;  w += (size_t)4096 * 512 * 2;
  _Float16* H2h  = (_Float16*)w;  w += (size_t)4096 * 1024 * 2;
  _Float16* TbH  = (_Float16*)w;  w += (size_t)4096 * 512 * 2;
  _Float16* PH   = (_Float16*)w;  w += (size_t)4096 * 1024 * 2;
  _Float16* w1tG = (_Float16*)w;  w += (size_t)48 * 64 * 2;
  _Float16* w2tG = (_Float16*)w;  w += (size_t)3 * 48 * 128 * 2;
  float* tl   = (float*)w;        w += (size_t)10 * NINST * 4;
  float* bet  = (float*)w;        w += (size_t)10 * NINST * 4;
  float* embs = (float*)w;        w += (size_t)10 * 1024 * 4;

  xform_w12<<<64, 256, 0, stream>>>(w1, w2, w1tG, w2tG);
  conv_fused<<<NINST, 256, 0, stream>>>(x, w1tG, w2tG, b1, b2, embh);

  gemm_h<1><<<dim3(16, 64), 256, 0, stream>>>(embh, fc1_w, fc1_b, H1h, 1728, 1728, 1728, 512);
  gemm_h<1><<<dim3(16, 64), 256, 0, stream>>>(H1h, fc2_w, fc2_b, H2h, 512, 512, 512, 1024);
  gemm_h<2><<<dim3(16, 64), 256, 0, stream>>>(H2h, nbr_w, nbr_b, TbH, 512, 1024, 512, 512);
  nbhd_k<<<1024, 256, 0, stream>>>(H2h, TbH);
  gemm_h<2><<<dim3(32, 64), 256, 0, stream>>>(H2h, proto_w, proto_b, PH, 1024, 1024, 1024, 1024);
  templ_scores<<<1024, 256, 0, stream>>>(PH, tmpl, tl);
  softmax_rows<<<10, 256, 0, stream>>>(tl, bet, embs);
  embs_k<<<dim3(4, 16), 256, 0, stream>>>(bet, H2h, embs);
  ga_k<<<1, 256, 0, stream>>>(embs, ga1_w, ga1_b, ga2_w, ga2_b, cls_w, cls_b, bet, out);
}

// Round 9
// 459.840 us; speedup vs baseline: 1.5290x; 1.2154x over previous
//
#include <hip/hip_runtime.h>
#include <math.h>

#define NINST 4096

typedef _Float16 half8 __attribute__((ext_vector_type(8)));
typedef _Float16 half4 __attribute__((ext_vector_type(4)));
typedef float floatx4 __attribute__((ext_vector_type(4)));

// ---------------------------------------------------------------------------
// xform_w12: w1 (36,3,4,4) -> w1t [48 oc][64], k = ky*16+kx*4+ic
//            w2 (48,36,3,3) -> w2t [3 ky][48 oc][128], k = kx*40+ic (k<120)
// zero-padded elsewhere. 64 blocks (grid-stride).
// ---------------------------------------------------------------------------
__global__ void xform_w12(const float* __restrict__ w1, const float* __restrict__ w2,
                          _Float16* __restrict__ w1t, _Float16* __restrict__ w2t) {
  for (int i = blockIdx.x * 256 + threadIdx.x; i < 48 * 64; i += gridDim.x * 256) {
    const int oc = i >> 6, k = i & 63;
    const int ky = k >> 4, r = k & 15, kx = r >> 2, ic = r & 3;
    float v = 0.f;
    if (oc < 36 && ic < 3) v = w1[((oc * 3 + ic) * 4 + ky) * 4 + kx];
    w1t[i] = (_Float16)v;
  }
  for (int i = blockIdx.x * 256 + threadIdx.x; i < 3 * 48 * 128; i += gridDim.x * 256) {
    const int ky = i / 6144, r = i % 6144;
    const int oc = r >> 7, k = r & 127;
    float v = 0.f;
    if (k < 120) {
      const int kx = k / 40, ic = k % 40;
      if (ic < 36) v = w2[((oc * 36 + ic) * 3 + ky) * 3 + kx];
    }
    w2t[i] = (_Float16)v;
  }
}

// ---------------------------------------------------------------------------
// MFMA conv, one block per instance.
// r8 lesson: `int mi=0; for(mt=wave;...;mi++) acc2[mi]` is a loop-carried
// dynamic index -> SROA fails -> acc2 lives in SCRATCH (VGPR_Count=48,
// WRITE_SIZE 302MB of scratch writebacks). Fix: unrolled mi with
// mt = wave + 4*mi (compile-time indices) so accumulators live in VGPRs.
// LDS: x_s 8KB + h1_s 15.4KB + h2_s 3.4KB = 26.8KB. 3 barriers per block.
// Pool-aligned m-map: m = window*4 + (dy*2+dx) -> C-quad regs = 2x2 window.
// ---------------------------------------------------------------------------
__launch_bounds__(256, 2)
__global__ void conv_fused(const float* __restrict__ x,
                           const _Float16* __restrict__ w1t_g,
                           const _Float16* __restrict__ w2t_g,
                           const float* __restrict__ b1, const float* __restrict__ b2,
                           _Float16* __restrict__ emb) {
  __shared__ __align__(16) _Float16 x_s[4096];      // [1024 pix][4 ch]
  __shared__ __align__(16) _Float16 h1_s[7856];     // [196 pix][40 ic] + 16 pad
  __shared__ __align__(16) _Float16 h2_s[1728];     // epilogue staging

  const int n = blockIdx.x, tid = threadIdx.x;
  const int lane = tid & 63, wave = tid >> 6;
  const int quad = lane >> 4, l15 = lane & 15;

  // ---- stage x: fp32 NCHW (nontemporal) -> fp16 channel-last [1024][4] ----
  {
    const float* xb = x + (size_t)n * 3072 + tid * 4;
    floatx4 xr0 = __builtin_nontemporal_load((const floatx4*)(xb));
    floatx4 xr1 = __builtin_nontemporal_load((const floatx4*)(xb + 1024));
    floatx4 xr2 = __builtin_nontemporal_load((const floatx4*)(xb + 2048));
    half8 pk0, pk1;
    pk0[0] = (_Float16)xr0[0]; pk0[1] = (_Float16)xr1[0]; pk0[2] = (_Float16)xr2[0]; pk0[3] = (_Float16)0.f;
    pk0[4] = (_Float16)xr0[1]; pk0[5] = (_Float16)xr1[1]; pk0[6] = (_Float16)xr2[1]; pk0[7] = (_Float16)0.f;
    pk1[0] = (_Float16)xr0[2]; pk1[1] = (_Float16)xr1[2]; pk1[2] = (_Float16)xr2[2]; pk1[3] = (_Float16)0.f;
    pk1[4] = (_Float16)xr0[3]; pk1[5] = (_Float16)xr1[3]; pk1[6] = (_Float16)xr2[3]; pk1[7] = (_Float16)0.f;
    *(half8*)&x_s[tid * 16] = pk0;
    *(half8*)&x_s[tid * 16 + 8] = pk1;
    if (tid < 16) h1_s[7840 + tid] = (_Float16)0.f;  // zero overrun pad
  }
  __syncthreads();

  // ---- conv1: M=784, N=48(36), K=64(48) -> h1 pooled+relu ----
  {
    half8 bc[2][3];
#pragma unroll
    for (int c = 0; c < 2; c++)
#pragma unroll
      for (int nt = 0; nt < 3; nt++)
        bc[c][nt] = *(const half8*)&w1t_g[(nt * 16 + l15) * 64 + c * 32 + quad * 8];
    float bia[3];
#pragma unroll
    for (int nt = 0; nt < 3; nt++) {
      const int oc = nt * 16 + l15;
      bia[nt] = (oc < 36) ? b1[oc] : 0.f;
    }
    for (int mt = wave; mt < 49; mt += 4) {
      const int mA = mt * 16 + l15;
      const int ppA = mA >> 2, dA = mA & 3;
      const int yA = 2 * (ppA / 14) + (dA >> 1);
      const int xA = 2 * (ppA % 14) + (dA & 1);
      floatx4 a1[3];
#pragma unroll
      for (int nt = 0; nt < 3; nt++)
#pragma unroll
        for (int r = 0; r < 4; r++) a1[nt][r] = 0.f;
#pragma unroll
      for (int c = 0; c < 2; c++) {
        const int row = yA + c * 2 + (quad >> 1);
        const half8 af = *(const half8*)&x_s[row * 128 + xA * 4 + (quad & 1) * 8];
#pragma unroll
        for (int nt = 0; nt < 3; nt++)
          a1[nt] = __builtin_amdgcn_mfma_f32_16x16x32_f16(af, bc[c][nt], a1[nt], 0, 0, 0);
      }
      const int ppC = mt * 4 + quad;
#pragma unroll
      for (int nt = 0; nt < 3; nt++) {
        const int oc = nt * 16 + l15;
        float v = fmaxf(fmaxf(a1[nt][0], a1[nt][1]), fmaxf(a1[nt][2], a1[nt][3])) + bia[nt];
        v = fmaxf(v, 0.f);
        if (oc < 40) h1_s[ppC * 40 + oc] = (_Float16)v;  // oc 36..39 write pad zeros
      }
    }
  }
  __syncthreads();   // h1 ready

  // ---- conv2: M=144, N=48, K=3ky x 128(120). Static acc indices! ----
  floatx4 acc2[3][3];
#pragma unroll
  for (int a = 0; a < 3; a++)
#pragma unroll
    for (int j = 0; j < 3; j++)
#pragma unroll
      for (int r = 0; r < 4; r++) acc2[a][j][r] = 0.f;

  for (int ky = 0; ky < 3; ky++) {
    half8 bc2[4][3];
#pragma unroll
    for (int c = 0; c < 4; c++)
#pragma unroll
      for (int nt = 0; nt < 3; nt++)
        bc2[c][nt] = *(const half8*)&w2t_g[ky * 6144 + (nt * 16 + l15) * 128 + c * 32 + quad * 8];
#pragma unroll
    for (int mi = 0; mi < 3; mi++) {
      const int mt = wave + 4 * mi;
      if (mt < 9) {
        const int mA = mt * 16 + l15;
        const int ppA = mA >> 2, dA = mA & 3;
        const int y2 = 2 * (ppA / 6) + (dA >> 1);
        const int x2 = 2 * (ppA % 6) + (dA & 1);
        const int rb = ((y2 + ky) * 14 + x2) * 40;
#pragma unroll
        for (int c = 0; c < 4; c++) {
          const half8 af = *(const half8*)&h1_s[rb + c * 32 + quad * 8];
#pragma unroll
          for (int nt = 0; nt < 3; nt++)
            acc2[mi][nt] = __builtin_amdgcn_mfma_f32_16x16x32_f16(af, bc2[c][nt], acc2[mi][nt], 0, 0, 0);
        }
      }
    }
  }

  // ---- pool in regs, stage to h2_s, write emb. Static indices again. ----
  {
    float bia2[3];
#pragma unroll
    for (int nt = 0; nt < 3; nt++) bia2[nt] = b2[nt * 16 + l15];
#pragma unroll
    for (int mi = 0; mi < 3; mi++) {
      const int mt = wave + 4 * mi;
      if (mt < 9) {
        const int ppC = mt * 4 + quad;
#pragma unroll
        for (int nt = 0; nt < 3; nt++) {
          const int oc = nt * 16 + l15;
          float v = fmaxf(fmaxf(acc2[mi][nt][0], acc2[mi][nt][1]),
                          fmaxf(acc2[mi][nt][2], acc2[mi][nt][3])) + bia2[nt];
          v = fmaxf(v, 0.f);
          h2_s[oc * 36 + ppC] = (_Float16)v;
        }
      }
    }
  }
  __syncthreads();   // epilogue staged (LDS drain only)
  if (tid < 216) {
    half8* dst = (half8*)(emb + (size_t)n * 1728);
    dst[tid] = ((const half8*)h2_s)[tid];
  }
}

// ---------------------------------------------------------------------------
// fp16-A x fp32-B MFMA GEMM: C[m,n] = act( sum_k A[m,k]*B[n,k] + bias[n] )
// BM=64, BN=32, BK=64, 256 threads. Single-barrier ping-pong K-loop; B fp32
// in global, converted to fp16 during staging (no separate cast pass).
// ACT: 0=none 1=relu 2=tanh.
// ---------------------------------------------------------------------------
template <int ACT>
__launch_bounds__(256, 4)
__global__ void gemm_h(const _Float16* __restrict__ A, const float* __restrict__ Bf,
                       const float* __restrict__ bias, _Float16* __restrict__ C,
                       int K, int lda, int ldb, int ldc) {
  __shared__ __align__(16) _Float16 As[2][64 * 72];
  __shared__ __align__(16) _Float16 Bs[2][32 * 72];
  const int tid = threadIdx.x;
  const int m0 = blockIdx.y * 64, n0 = blockIdx.x * 32;
  const int lane = tid & 63, wave = tid >> 6;
  const int quad = lane >> 4, l15 = lane & 15;
  const int wm = (wave >> 1) * 32, wn = (wave & 1) * 16;
  const int arow = tid >> 2, acol = (tid & 3) * 16;   // 64 rows x 16 halves
  const int brow = tid >> 3, bcol = (tid & 7) * 8;    // 32 rows x 8 floats

  const _Float16* Ap = A + (size_t)(m0 + arow) * lda + acol;
  const float* Bp = Bf + (size_t)(n0 + brow) * ldb + bcol;

  half8 av0 = *(const half8*)(Ap);
  half8 av1 = *(const half8*)(Ap + 8);
  floatx4 bv0 = *(const floatx4*)(Bp);
  floatx4 bv1 = *(const floatx4*)(Bp + 4);

  floatx4 acc[2];
#pragma unroll
  for (int a = 0; a < 2; a++)
#pragma unroll
    for (int r = 0; r < 4; r++) acc[a][r] = 0.f;

  int buf = 0;
  for (int k0 = 0; k0 < K; k0 += 64) {
    *(half8*)&As[buf][arow * 72 + acol] = av0;
    *(half8*)&As[buf][arow * 72 + acol + 8] = av1;
    {
      half8 bh;
      bh[0] = (_Float16)bv0[0]; bh[1] = (_Float16)bv0[1];
      bh[2] = (_Float16)bv0[2]; bh[3] = (_Float16)bv0[3];
      bh[4] = (_Float16)bv1[0]; bh[5] = (_Float16)bv1[1];
      bh[6] = (_Float16)bv1[2]; bh[7] = (_Float16)bv1[3];
      *(half8*)&Bs[buf][brow * 72 + bcol] = bh;
    }
    __syncthreads();
    if (k0 + 64 < K) {
      av0 = *(const half8*)(Ap + k0 + 64);
      av1 = *(const half8*)(Ap + k0 + 64 + 8);
      bv0 = *(const floatx4*)(Bp + k0 + 64);
      bv1 = *(const floatx4*)(Bp + k0 + 64 + 4);
    }
#pragma unroll
    for (int ks = 0; ks < 64; ks += 32) {
      const half8 af0 = *(const half8*)&As[buf][(wm + l15) * 72 + ks + quad * 8];
      const half8 af1 = *(const half8*)&As[buf][(wm + 16 + l15) * 72 + ks + quad * 8];
      const half8 bf0 = *(const half8*)&Bs[buf][(wn + l15) * 72 + ks + quad * 8];
      acc[0] = __builtin_amdgcn_mfma_f32_16x16x32_f16(af0, bf0, acc[0], 0, 0, 0);
      acc[1] = __builtin_amdgcn_mfma_f32_16x16x32_f16(af1, bf0, acc[1], 0, 0, 0);
    }
    buf ^= 1;
  }

  const int col = n0 + wn + l15;
  const float bcolv = bias[col];
#pragma unroll
  for (int mt = 0; mt < 2; mt++) {
#pragma unroll
    for (int r = 0; r < 4; r++) {
      const int row = m0 + wm + mt * 16 + quad * 4 + r;
      float v = acc[mt][r] + bcolv;
      if (ACT == 1) v = fmaxf(v, 0.f);
      if (ACT == 2) v = tanhf(v);
      C[(size_t)row * ldc + col] = (_Float16)v;
    }
  }
}

// ---------------------------------------------------------------------------
// Neighborhood attention: one wave per instance. <=8 grid neighbors.
// ---------------------------------------------------------------------------
__launch_bounds__(256)
__global__ void nbhd_k(_Float16* __restrict__ H2, const _Float16* __restrict__ T) {
  const int wid = (blockIdx.x * 256 + threadIdx.x) >> 6;
  const int lane = threadIdx.x & 63;
  const int r = wid >> 6, c = wid & 63;
  const _Float16* hi = H2 + (size_t)wid * 1024;
  float hreg[8];
#pragma unroll
  for (int u = 0; u < 8; u++) hreg[u] = (float)hi[u * 64 + lane];

  float sv[8];
  int jv[8];
  bool ok[8];
  int q = 0;
#pragma unroll
  for (int dr = -1; dr <= 1; dr++)
#pragma unroll
    for (int dc = -1; dc <= 1; dc++) {
      if (dr == 0 && dc == 0) continue;
      const int rr = r + dr, cc = c + dc;
      const bool v = (rr >= 0) && (rr < 64) && (cc >= 0) && (cc < 64);
      const int j = v ? (rr * 64 + cc) : wid;
      const _Float16* tj = T + (size_t)j * 512;
      float s = 0.f;
#pragma unroll
      for (int u = 0; u < 8; u++) s = fmaf(hreg[u], (float)tj[u * 64 + lane], s);
#pragma unroll
      for (int off = 32; off > 0; off >>= 1) s += __shfl_xor(s, off, 64);
      sv[q] = v ? s : -3.4e38f;
      jv[q] = j;
      ok[q] = v;
      q++;
    }

  float m = sv[0];
#pragma unroll
  for (int a = 1; a < 8; a++) m = fmaxf(m, sv[a]);
  float e[8], den = 0.f;
#pragma unroll
  for (int a = 0; a < 8; a++) {
    e[a] = ok[a] ? expf(sv[a] - m) : 0.f;
    den += e[a];
  }
  const float inv = 1.f / den;

  float outv[8];
#pragma unroll
  for (int u = 0; u < 8; u++) outv[u] = 0.f;
#pragma unroll
  for (int a = 0; a < 8; a++) {
    const float al = e[a] * inv;
    const _Float16* hj = H2 + (size_t)jv[a] * 1024;
#pragma unroll
    for (int u = 0; u < 8; u++) outv[u] = fmaf(al, (float)hj[u * 64 + lane], outv[u]);
  }
  _Float16* dst = H2 + (size_t)wid * 1024 + 512;
#pragma unroll
  for (int u = 0; u < 8; u++) dst[u * 64 + lane] = (_Float16)outv[u];
}

// ---------------------------------------------------------------------------
// tl[t,n] = P[n,:] . templates[t,:]
// ---------------------------------------------------------------------------
__launch_bounds__(256)
__global__ void templ_scores(const _Float16* __restrict__ P, const float* __restrict__ tmpl,
                             float* __restrict__ tl) {
  const int wid = (blockIdx.x * 256 + threadIdx.x) >> 6;
  const int lane = threadIdx.x & 63;
  const _Float16* p = P + (size_t)wid * 1024;
  float pr[16];
#pragma unroll
  for (int u = 0; u < 16; u++) pr[u] = (float)p[u * 64 + lane];
  for (int t = 0; t < 10; t++) {
    const float* tp = tmpl + t * 1024;
    float s = 0.f;
#pragma unroll
    for (int u = 0; u < 16; u++) s = fmaf(pr[u], tp[u * 64 + lane], s);
#pragma unroll
    for (int off = 32; off > 0; off >>= 1) s += __shfl_xor(s, off, 64);
    if (lane == 0) tl[t * NINST + wid] = s;
  }
}

// ---------------------------------------------------------------------------
// Per-template softmax over N=4096; also zeros embs rows (for embs_k atomics)
// ---------------------------------------------------------------------------
__launch_bounds__(256)
__global__ void softmax_rows(const float* __restrict__ tl, float* __restrict__ betas,
                             float* __restrict__ embs) {
  const int t = blockIdx.x, tid = threadIdx.x;
  __shared__ float red[256];
  for (int i = tid; i < 1024; i += 256) embs[t * 1024 + i] = 0.f;
  const float* row = tl + t * NINST;
  float m = -3.4e38f;
  for (int i = tid; i < NINST; i += 256) m = fmaxf(m, row[i]);
  red[tid] = m;
  __syncthreads();
  for (int s = 128; s > 0; s >>= 1) {
    if (tid < s) red[tid] = fmaxf(red[tid], red[tid + s]);
    __syncthreads();
  }
  m = red[0];
  __syncthreads();
  float sum = 0.f;
  for (int i = tid; i < NINST; i += 256) sum += expf(row[i] - m);
  red[tid] = sum;
  __syncthreads();
  for (int s = 128; s > 0; s >>= 1) {
    if (tid < s) red[tid] += red[tid + s];
    __syncthreads();
  }
  const float inv = 1.f / red[0];
  for (int i = tid; i < NINST; i += 256) betas[t * NINST + i] = expf(row[i] - m) * inv;
}

// ---------------------------------------------------------------------------
// embs[t,k] += sum_{n in slice} betas[t,n] * H2h[n,k]
// ---------------------------------------------------------------------------
__launch_bounds__(256)
__global__ void embs_k(const float* __restrict__ betas, const _Float16* __restrict__ H2,
                       float* __restrict__ embs) {
  const int k = blockIdx.x * 256 + threadIdx.x;
  const int nbase = blockIdx.y * 256;
  float acc[10];
#pragma unroll
  for (int t = 0; t < 10; t++) acc[t] = 0.f;
  for (int n = nbase; n < nbase + 256; n++) {
    const float v = (float)H2[(size_t)n * 1024 + k];
#pragma unroll
    for (int t = 0; t < 10; t++) acc[t] = fmaf(betas[t * NINST + n], v, acc[t]);
  }
#pragma unroll
  for (int t = 0; t < 10; t++) atomicAdd(&embs[t * 1024 + k], acc[t]);
}

// ---------------------------------------------------------------------------
// Global attention tail: g, gammas, M, Y_prob, Y_hat, and A (fused a_k).
// out[0]=Y_prob, out[1]=Y_hat, out[2..4098]=A. Single block.
// ---------------------------------------------------------------------------
__launch_bounds__(256)
__global__ void ga_k(const float* __restrict__ embs_g, const float* __restrict__ ga1_w,
                     const float* __restrict__ ga1_b, const float* __restrict__ ga2_w,
                     const float* __restrict__ ga2_b, const float* __restrict__ cls_w,
                     const float* __restrict__ cls_b, const float* __restrict__ betas,
                     float* __restrict__ out) {
  __shared__ __align__(16) float embs_s[10 * 1024];
  __shared__ float hh[10 * 128];
  __shared__ float red[256];
  __shared__ float g_s[10], gam_s[10];
  __shared__ float M_s[1024];
  const int tid = threadIdx.x;
  const int wave = tid >> 6, lane = tid & 63;

  for (int i = tid; i < 10240; i += 256) embs_s[i] = embs_g[i];
  __syncthreads();

  for (int j = 0; j < 32; j++) {
    const int d = wave * 32 + j;
    float wreg[16];
#pragma unroll
    for (int u = 0; u < 16; u++) wreg[u] = ga1_w[(size_t)d * 1024 + u * 64 + lane];
    const float bd = ga1_b[d];
    for (int t = 0; t < 10; t++) {
      float s = 0.f;
#pragma unroll
      for (int u = 0; u < 16; u++) s = fmaf(wreg[u], embs_s[t * 1024 + u * 64 + lane], s);
#pragma unroll
      for (int off = 32; off > 0; off >>= 1) s += __shfl_xor(s, off, 64);
      if (lane == 0) hh[t * 128 + d] = tanhf(s + bd);
    }
  }
  __syncthreads();

  if (wave == 0) {
    for (int t = 0; t < 10; t++) {
      float s = hh[t * 128 + lane] * ga2_w[lane] + hh[t * 128 + 64 + lane] * ga2_w[64 + lane];
#pragma unroll
      for (int off = 32; off > 0; off >>= 1) s += __shfl_xor(s, off, 64);
      if (lane == 0) g_s[t] = s + ga2_b[0];
    }
  }
  __syncthreads();

  if (tid == 0) {
    float m = g_s[0];
    for (int t = 1; t < 10; t++) m = fmaxf(m, g_s[t]);
    float sum = 0.f;
    for (int t = 0; t < 10; t++) sum += expf(g_s[t] - m);
    for (int t = 0; t < 10; t++) gam_s[t] = expf(g_s[t] - m) / sum;
  }
  __syncthreads();

  // A[n] = sum_t gam[t]*betas[t,n]   (fused former a_k)
  for (int nn = tid; nn < NINST; nn += 256) {
    float a = 0.f;
#pragma unroll
    for (int t = 0; t < 10; t++) a = fmaf(gam_s[t], betas[t * NINST + nn], a);
    out[2 + nn] = a;
  }

  for (int k = tid; k < 1024; k += 256) {
    float a = 0.f;
#pragma unroll
    for (int t = 0; t < 10; t++) a = fmaf(gam_s[t], embs_s[t * 1024 + k], a);
    M_s[k] = a;
  }
  __syncthreads();

  float part = 0.f;
  for (int k = tid; k < 1024; k += 256) part = fmaf(M_s[k], cls_w[k], part);
  red[tid] = part;
  __syncthreads();
  for (int s = 128; s > 0; s >>= 1) {
    if (tid < s) red[tid] += red[tid + s];
    __syncthreads();
  }
  if (tid == 0) {
    const float z = red[0] + cls_b[0];
    const float yp = 1.f / (1.f + expf(-z));
    out[0] = yp;
    out[1] = (yp >= 0.5f) ? 1.f : 0.f;
  }
}

// ---------------------------------------------------------------------------
extern "C" void kernel_launch(void* const* d_in, const int* in_sizes, int n_in,
                              void* d_out, int out_size, void* d_ws, size_t ws_size,
                              hipStream_t stream) {
  const float* x       = (const float*)d_in[0];
  const float* w1      = (const float*)d_in[2];
  const float* b1      = (const float*)d_in[3];
  const float* w2      = (const float*)d_in[4];
  const float* b2      = (const float*)d_in[5];
  const float* fc1_w   = (const float*)d_in[6];
  const float* fc1_b   = (const float*)d_in[7];
  const float* fc2_w   = (const float*)d_in[8];
  const float* fc2_b   = (const float*)d_in[9];
  const float* nbr_w   = (const float*)d_in[10];
  const float* nbr_b   = (const float*)d_in[11];
  const float* tmpl    = (const float*)d_in[12];
  const float* proto_w = (const float*)d_in[13];
  const float* proto_b = (const float*)d_in[14];
  const float* ga1_w   = (const float*)d_in[15];
  const float* ga1_b   = (const float*)d_in[16];
  const float* ga2_w   = (const float*)d_in[17];
  const float* ga2_b   = (const float*)d_in[18];
  const float* cls_w   = (const float*)d_in[19];
  const float* cls_b   = (const float*)d_in[20];
  float* out = (float*)d_out;

  char* w = (char*)d_ws;
  _Float16* embh = (_Float16*)w;  w += (size_t)4096 * 1728 * 2;
  _Float16* H1h  = (_Float16*)w;  w += (size_t)4096 * 512 * 2;
  _Float16* H2h  = (_Float16*)w;  w += (size_t)4096 * 1024 * 2;
  _Float16* TbH  = (_Float16*)w;  w += (size_t)4096 * 512 * 2;
  _Float16* PH   = (_Float16*)w;  w += (size_t)4096 * 1024 * 2;
  _Float16* w1tG = (_Float16*)w;  w += (size_t)48 * 64 * 2;
  _Float16* w2tG = (_Float16*)w;  w += (size_t)3 * 48 * 128 * 2;
  float* tl   = (float*)w;        w += (size_t)10 * NINST * 4;
  float* bet  = (float*)w;        w += (size_t)10 * NINST * 4;
  float* embs = (float*)w;        w += (size_t)10 * 1024 * 4;

  xform_w12<<<64, 256, 0, stream>>>(w1, w2, w1tG, w2tG);
  conv_fused<<<NINST, 256, 0, stream>>>(x, w1tG, w2tG, b1, b2, embh);

  gemm_h<1><<<dim3(16, 64), 256, 0, stream>>>(embh, fc1_w, fc1_b, H1h, 1728, 1728, 1728, 512);
  gemm_h<1><<<dim3(16, 64), 256, 0, stream>>>(H1h, fc2_w, fc2_b, H2h, 512, 512, 512, 1024);
  gemm_h<2><<<dim3(16, 64), 256, 0, stream>>>(H2h, nbr_w, nbr_b, TbH, 512, 1024, 512, 512);
  nbhd_k<<<1024, 256, 0, stream>>>(H2h, TbH);
  gemm_h<2><<<dim3(32, 64), 256, 0, stream>>>(H2h, proto_w, proto_b, PH, 1024, 1024, 1024, 1024);
  templ_scores<<<1024, 256, 0, stream>>>(PH, tmpl, tl);
  softmax_rows<<<10, 256, 0, stream>>>(tl, bet, embs);
  embs_k<<<dim3(4, 16), 256, 0, stream>>>(bet, H2h, embs);
  ga_k<<<1, 256, 0, stream>>>(embs, ga1_w, ga1_b, ga2_w, ga2_b, cls_w, cls_b, bet, out);
}

// Round 10
// 357.071 us; speedup vs baseline: 1.9691x; 1.2878x over previous
//
#include <hip/hip_runtime.h>
#include <math.h>

#define NINST 4096

typedef _Float16 half8 __attribute__((ext_vector_type(8)));
typedef _Float16 half4 __attribute__((ext_vector_type(4)));
typedef float floatx4 __attribute__((ext_vector_type(4)));

// ---------------------------------------------------------------------------
// xform_w12: w1 (36,3,4,4) -> w1t [48 oc][64], k = ky*16+kx*4+ic
//            w2 (48,36,3,3) -> w2t [3 ky][48 oc][128], k = kx*40+ic (k<120)
// zero-padded elsewhere. 64 blocks (grid-stride).
// ---------------------------------------------------------------------------
__global__ void xform_w12(const float* __restrict__ w1, const float* __restrict__ w2,
                          _Float16* __restrict__ w1t, _Float16* __restrict__ w2t) {
  for (int i = blockIdx.x * 256 + threadIdx.x; i < 48 * 64; i += gridDim.x * 256) {
    const int oc = i >> 6, k = i & 63;
    const int ky = k >> 4, r = k & 15, kx = r >> 2, ic = r & 3;
    float v = 0.f;
    if (oc < 36 && ic < 3) v = w1[((oc * 3 + ic) * 4 + ky) * 4 + kx];
    w1t[i] = (_Float16)v;
  }
  for (int i = blockIdx.x * 256 + threadIdx.x; i < 3 * 48 * 128; i += gridDim.x * 256) {
    const int ky = i / 6144, r = i % 6144;
    const int oc = r >> 7, k = r & 127;
    float v = 0.f;
    if (k < 120) {
      const int kx = k / 40, ic = k % 40;
      if (ic < 36) v = w2[((oc * 36 + ic) * 3 + ky) * 3 + kx];
    }
    w2t[i] = (_Float16)v;
  }
}

// ---------------------------------------------------------------------------
// MFMA conv, one block per instance. Static accumulator indices (r8 lesson:
// loop-carried dynamic index -> scratch). LDS 26.8KB, 3 barriers.
// Pool-aligned m-map: m = window*4 + (dy*2+dx) -> C-quad regs = 2x2 window.
// ---------------------------------------------------------------------------
__launch_bounds__(256, 2)
__global__ void conv_fused(const float* __restrict__ x,
                           const _Float16* __restrict__ w1t_g,
                           const _Float16* __restrict__ w2t_g,
                           const float* __restrict__ b1, const float* __restrict__ b2,
                           _Float16* __restrict__ emb) {
  __shared__ __align__(16) _Float16 x_s[4096];      // [1024 pix][4 ch]
  __shared__ __align__(16) _Float16 h1_s[7856];     // [196 pix][40 ic] + 16 pad
  __shared__ __align__(16) _Float16 h2_s[1728];     // epilogue staging

  const int n = blockIdx.x, tid = threadIdx.x;
  const int lane = tid & 63, wave = tid >> 6;
  const int quad = lane >> 4, l15 = lane & 15;

  // ---- stage x: fp32 NCHW (nontemporal) -> fp16 channel-last [1024][4] ----
  {
    const float* xb = x + (size_t)n * 3072 + tid * 4;
    floatx4 xr0 = __builtin_nontemporal_load((const floatx4*)(xb));
    floatx4 xr1 = __builtin_nontemporal_load((const floatx4*)(xb + 1024));
    floatx4 xr2 = __builtin_nontemporal_load((const floatx4*)(xb + 2048));
    half8 pk0, pk1;
    pk0[0] = (_Float16)xr0[0]; pk0[1] = (_Float16)xr1[0]; pk0[2] = (_Float16)xr2[0]; pk0[3] = (_Float16)0.f;
    pk0[4] = (_Float16)xr0[1]; pk0[5] = (_Float16)xr1[1]; pk0[6] = (_Float16)xr2[1]; pk0[7] = (_Float16)0.f;
    pk1[0] = (_Float16)xr0[2]; pk1[1] = (_Float16)xr1[2]; pk1[2] = (_Float16)xr2[2]; pk1[3] = (_Float16)0.f;
    pk1[4] = (_Float16)xr0[3]; pk1[5] = (_Float16)xr1[3]; pk1[6] = (_Float16)xr2[3]; pk1[7] = (_Float16)0.f;
    *(half8*)&x_s[tid * 16] = pk0;
    *(half8*)&x_s[tid * 16 + 8] = pk1;
    if (tid < 16) h1_s[7840 + tid] = (_Float16)0.f;  // zero overrun pad
  }
  __syncthreads();

  // ---- conv1: M=784, N=48(36), K=64(48) -> h1 pooled+relu ----
  {
    half8 bc[2][3];
#pragma unroll
    for (int c = 0; c < 2; c++)
#pragma unroll
      for (int nt = 0; nt < 3; nt++)
        bc[c][nt] = *(const half8*)&w1t_g[(nt * 16 + l15) * 64 + c * 32 + quad * 8];
    float bia[3];
#pragma unroll
    for (int nt = 0; nt < 3; nt++) {
      const int oc = nt * 16 + l15;
      bia[nt] = (oc < 36) ? b1[oc] : 0.f;
    }
    for (int mt = wave; mt < 49; mt += 4) {
      const int mA = mt * 16 + l15;
      const int ppA = mA >> 2, dA = mA & 3;
      const int yA = 2 * (ppA / 14) + (dA >> 1);
      const int xA = 2 * (ppA % 14) + (dA & 1);
      floatx4 a1[3];
#pragma unroll
      for (int nt = 0; nt < 3; nt++)
#pragma unroll
        for (int r = 0; r < 4; r++) a1[nt][r] = 0.f;
#pragma unroll
      for (int c = 0; c < 2; c++) {
        const int row = yA + c * 2 + (quad >> 1);
        const half8 af = *(const half8*)&x_s[row * 128 + xA * 4 + (quad & 1) * 8];
#pragma unroll
        for (int nt = 0; nt < 3; nt++)
          a1[nt] = __builtin_amdgcn_mfma_f32_16x16x32_f16(af, bc[c][nt], a1[nt], 0, 0, 0);
      }
      const int ppC = mt * 4 + quad;
#pragma unroll
      for (int nt = 0; nt < 3; nt++) {
        const int oc = nt * 16 + l15;
        float v = fmaxf(fmaxf(a1[nt][0], a1[nt][1]), fmaxf(a1[nt][2], a1[nt][3])) + bia[nt];
        v = fmaxf(v, 0.f);
        if (oc < 40) h1_s[ppC * 40 + oc] = (_Float16)v;  // oc 36..39 write pad zeros
      }
    }
  }
  __syncthreads();   // h1 ready

  // ---- conv2: M=144, N=48, K=3ky x 128(120). Static acc indices! ----
  floatx4 acc2[3][3];
#pragma unroll
  for (int a = 0; a < 3; a++)
#pragma unroll
    for (int j = 0; j < 3; j++)
#pragma unroll
      for (int r = 0; r < 4; r++) acc2[a][j][r] = 0.f;

  for (int ky = 0; ky < 3; ky++) {
    half8 bc2[4][3];
#pragma unroll
    for (int c = 0; c < 4; c++)
#pragma unroll
      for (int nt = 0; nt < 3; nt++)
        bc2[c][nt] = *(const half8*)&w2t_g[ky * 6144 + (nt * 16 + l15) * 128 + c * 32 + quad * 8];
#pragma unroll
    for (int mi = 0; mi < 3; mi++) {
      const int mt = wave + 4 * mi;
      if (mt < 9) {
        const int mA = mt * 16 + l15;
        const int ppA = mA >> 2, dA = mA & 3;
        const int y2 = 2 * (ppA / 6) + (dA >> 1);
        const int x2 = 2 * (ppA % 6) + (dA & 1);
        const int rb = ((y2 + ky) * 14 + x2) * 40;
#pragma unroll
        for (int c = 0; c < 4; c++) {
          const half8 af = *(const half8*)&h1_s[rb + c * 32 + quad * 8];
#pragma unroll
          for (int nt = 0; nt < 3; nt++)
            acc2[mi][nt] = __builtin_amdgcn_mfma_f32_16x16x32_f16(af, bc2[c][nt], acc2[mi][nt], 0, 0, 0);
        }
      }
    }
  }

  // ---- pool in regs, stage to h2_s, write emb. Static indices again. ----
  {
    float bia2[3];
#pragma unroll
    for (int nt = 0; nt < 3; nt++) bia2[nt] = b2[nt * 16 + l15];
#pragma unroll
    for (int mi = 0; mi < 3; mi++) {
      const int mt = wave + 4 * mi;
      if (mt < 9) {
        const int ppC = mt * 4 + quad;
#pragma unroll
        for (int nt = 0; nt < 3; nt++) {
          const int oc = nt * 16 + l15;
          float v = fmaxf(fmaxf(acc2[mi][nt][0], acc2[mi][nt][1]),
                          fmaxf(acc2[mi][nt][2], acc2[mi][nt][3])) + bia2[nt];
          v = fmaxf(v, 0.f);
          h2_s[oc * 36 + ppC] = (_Float16)v;
        }
      }
    }
  }
  __syncthreads();   // epilogue staged (LDS drain only)
  if (tid < 216) {
    half8* dst = (half8*)(emb + (size_t)n * 1728);
    dst[tid] = ((const half8*)h2_s)[tid];
  }
}

// ---------------------------------------------------------------------------
// fp16-A x fp32-B MFMA GEMM: C[m,n] = act( sum_k A[m,k]*B[n,k] + bias[n] )
// BM=64, BN=32, BK=64, 256 threads. Single-barrier ping-pong K-loop; B fp32
// in global, converted to fp16 during staging. ACT: 0=none 1=relu 2=tanh.
// ---------------------------------------------------------------------------
template <int ACT>
__launch_bounds__(256, 4)
__global__ void gemm_h(const _Float16* __restrict__ A, const float* __restrict__ Bf,
                       const float* __restrict__ bias, _Float16* __restrict__ C,
                       int K, int lda, int ldb, int ldc) {
  __shared__ __align__(16) _Float16 As[2][64 * 72];
  __shared__ __align__(16) _Float16 Bs[2][32 * 72];
  const int tid = threadIdx.x;
  const int m0 = blockIdx.y * 64, n0 = blockIdx.x * 32;
  const int lane = tid & 63, wave = tid >> 6;
  const int quad = lane >> 4, l15 = lane & 15;
  const int wm = (wave >> 1) * 32, wn = (wave & 1) * 16;
  const int arow = tid >> 2, acol = (tid & 3) * 16;   // 64 rows x 16 halves
  const int brow = tid >> 3, bcol = (tid & 7) * 8;    // 32 rows x 8 floats

  const _Float16* Ap = A + (size_t)(m0 + arow) * lda + acol;
  const float* Bp = Bf + (size_t)(n0 + brow) * ldb + bcol;

  half8 av0 = *(const half8*)(Ap);
  half8 av1 = *(const half8*)(Ap + 8);
  floatx4 bv0 = *(const floatx4*)(Bp);
  floatx4 bv1 = *(const floatx4*)(Bp + 4);

  floatx4 acc[2];
#pragma unroll
  for (int a = 0; a < 2; a++)
#pragma unroll
    for (int r = 0; r < 4; r++) acc[a][r] = 0.f;

  int buf = 0;
  for (int k0 = 0; k0 < K; k0 += 64) {
    *(half8*)&As[buf][arow * 72 + acol] = av0;
    *(half8*)&As[buf][arow * 72 + acol + 8] = av1;
    {
      half8 bh;
      bh[0] = (_Float16)bv0[0]; bh[1] = (_Float16)bv0[1];
      bh[2] = (_Float16)bv0[2]; bh[3] = (_Float16)bv0[3];
      bh[4] = (_Float16)bv1[0]; bh[5] = (_Float16)bv1[1];
      bh[6] = (_Float16)bv1[2]; bh[7] = (_Float16)bv1[3];
      *(half8*)&Bs[buf][brow * 72 + bcol] = bh;
    }
    __syncthreads();
    if (k0 + 64 < K) {
      av0 = *(const half8*)(Ap + k0 + 64);
      av1 = *(const half8*)(Ap + k0 + 64 + 8);
      bv0 = *(const floatx4*)(Bp + k0 + 64);
      bv1 = *(const floatx4*)(Bp + k0 + 64 + 4);
    }
#pragma unroll
    for (int ks = 0; ks < 64; ks += 32) {
      const half8 af0 = *(const half8*)&As[buf][(wm + l15) * 72 + ks + quad * 8];
      const half8 af1 = *(const half8*)&As[buf][(wm + 16 + l15) * 72 + ks + quad * 8];
      const half8 bf0 = *(const half8*)&Bs[buf][(wn + l15) * 72 + ks + quad * 8];
      acc[0] = __builtin_amdgcn_mfma_f32_16x16x32_f16(af0, bf0, acc[0], 0, 0, 0);
      acc[1] = __builtin_amdgcn_mfma_f32_16x16x32_f16(af1, bf0, acc[1], 0, 0, 0);
    }
    buf ^= 1;
  }

  const int col = n0 + wn + l15;
  const float bcolv = bias[col];
#pragma unroll
  for (int mt = 0; mt < 2; mt++) {
#pragma unroll
    for (int r = 0; r < 4; r++) {
      const int row = m0 + wm + mt * 16 + quad * 4 + r;
      float v = acc[mt][r] + bcolv;
      if (ACT == 1) v = fmaxf(v, 0.f);
      if (ACT == 2) v = tanhf(v);
      C[(size_t)row * ldc + col] = (_Float16)v;
    }
  }
}

// ---------------------------------------------------------------------------
// Neighborhood attention: one wave per instance. <=8 grid neighbors.
// ---------------------------------------------------------------------------
__launch_bounds__(256)
__global__ void nbhd_k(_Float16* __restrict__ H2, const _Float16* __restrict__ T) {
  const int wid = (blockIdx.x * 256 + threadIdx.x) >> 6;
  const int lane = threadIdx.x & 63;
  const int r = wid >> 6, c = wid & 63;
  const _Float16* hi = H2 + (size_t)wid * 1024;
  float hreg[8];
#pragma unroll
  for (int u = 0; u < 8; u++) hreg[u] = (float)hi[u * 64 + lane];

  float sv[8];
  int jv[8];
  bool ok[8];
  int q = 0;
#pragma unroll
  for (int dr = -1; dr <= 1; dr++)
#pragma unroll
    for (int dc = -1; dc <= 1; dc++) {
      if (dr == 0 && dc == 0) continue;
      const int rr = r + dr, cc = c + dc;
      const bool v = (rr >= 0) && (rr < 64) && (cc >= 0) && (cc < 64);
      const int j = v ? (rr * 64 + cc) : wid;
      const _Float16* tj = T + (size_t)j * 512;
      float s = 0.f;
#pragma unroll
      for (int u = 0; u < 8; u++) s = fmaf(hreg[u], (float)tj[u * 64 + lane], s);
#pragma unroll
      for (int off = 32; off > 0; off >>= 1) s += __shfl_xor(s, off, 64);
      sv[q] = v ? s : -3.4e38f;
      jv[q] = j;
      ok[q] = v;
      q++;
    }

  float m = sv[0];
#pragma unroll
  for (int a = 1; a < 8; a++) m = fmaxf(m, sv[a]);
  float e[8], den = 0.f;
#pragma unroll
  for (int a = 0; a < 8; a++) {
    e[a] = ok[a] ? expf(sv[a] - m) : 0.f;
    den += e[a];
  }
  const float inv = 1.f / den;

  float outv[8];
#pragma unroll
  for (int u = 0; u < 8; u++) outv[u] = 0.f;
#pragma unroll
  for (int a = 0; a < 8; a++) {
    const float al = e[a] * inv;
    const _Float16* hj = H2 + (size_t)jv[a] * 1024;
#pragma unroll
    for (int u = 0; u < 8; u++) outv[u] = fmaf(al, (float)hj[u * 64 + lane], outv[u]);
  }
  _Float16* dst = H2 + (size_t)wid * 1024 + 512;
#pragma unroll
  for (int u = 0; u < 8; u++) dst[u * 64 + lane] = (_Float16)outv[u];
}

// ---------------------------------------------------------------------------
// tl[t,n] = P[n,:] . templates[t,:]
// ---------------------------------------------------------------------------
__launch_bounds__(256)
__global__ void templ_scores(const _Float16* __restrict__ P, const float* __restrict__ tmpl,
                             float* __restrict__ tl) {
  const int wid = (blockIdx.x * 256 + threadIdx.x) >> 6;
  const int lane = threadIdx.x & 63;
  const _Float16* p = P + (size_t)wid * 1024;
  float pr[16];
#pragma unroll
  for (int u = 0; u < 16; u++) pr[u] = (float)p[u * 64 + lane];
  for (int t = 0; t < 10; t++) {
    const float* tp = tmpl + t * 1024;
    float s = 0.f;
#pragma unroll
    for (int u = 0; u < 16; u++) s = fmaf(pr[u], tp[u * 64 + lane], s);
#pragma unroll
    for (int off = 32; off > 0; off >>= 1) s += __shfl_xor(s, off, 64);
    if (lane == 0) tl[t * NINST + wid] = s;
  }
}

// ---------------------------------------------------------------------------
// Per-template softmax over N=4096; also zeros embs rows (for embs_k atomics)
// ---------------------------------------------------------------------------
__launch_bounds__(256)
__global__ void softmax_rows(const float* __restrict__ tl, float* __restrict__ betas,
                             float* __restrict__ embs) {
  const int t = blockIdx.x, tid = threadIdx.x;
  __shared__ float red[256];
  for (int i = tid; i < 1024; i += 256) embs[t * 1024 + i] = 0.f;
  const float* row = tl + t * NINST;
  float m = -3.4e38f;
  for (int i = tid; i < NINST; i += 256) m = fmaxf(m, row[i]);
  red[tid] = m;
  __syncthreads();
  for (int s = 128; s > 0; s >>= 1) {
    if (tid < s) red[tid] = fmaxf(red[tid], red[tid + s]);
    __syncthreads();
  }
  m = red[0];
  __syncthreads();
  float sum = 0.f;
  for (int i = tid; i < NINST; i += 256) sum += expf(row[i] - m);
  red[tid] = sum;
  __syncthreads();
  for (int s = 128; s > 0; s >>= 1) {
    if (tid < s) red[tid] += red[tid + s];
    __syncthreads();
  }
  const float inv = 1.f / red[0];
  for (int i = tid; i < NINST; i += 256) betas[t * NINST + i] = expf(row[i] - m) * inv;
}

// ---------------------------------------------------------------------------
// embs[t,k] += sum_{n in slice} betas[t,n] * H2h[n,k]
// ---------------------------------------------------------------------------
__launch_bounds__(256)
__global__ void embs_k(const float* __restrict__ betas, const _Float16* __restrict__ H2,
                       float* __restrict__ embs) {
  const int k = blockIdx.x * 256 + threadIdx.x;
  const int nbase = blockIdx.y * 256;
  float acc[10];
#pragma unroll
  for (int t = 0; t < 10; t++) acc[t] = 0.f;
  for (int n = nbase; n < nbase + 256; n++) {
    const float v = (float)H2[(size_t)n * 1024 + k];
#pragma unroll
    for (int t = 0; t < 10; t++) acc[t] = fmaf(betas[t * NINST + n], v, acc[t]);
  }
#pragma unroll
  for (int t = 0; t < 10; t++) atomicAdd(&embs[t * 1024 + k], acc[t]);
}

// ---------------------------------------------------------------------------
// ga1_k: hh[t,d] = tanh(embs[t,:].ga1_w[d,:] + ga1_b[d]).  One block per d
// (grid 128). Coalesced ga1_w reads; per-thread 10-way partials; wave shfl
// reduce + cross-wave LDS combine.
// ---------------------------------------------------------------------------
__launch_bounds__(256)
__global__ void ga1_k(const float* __restrict__ embs, const float* __restrict__ ga1_w,
                      const float* __restrict__ ga1_b, float* __restrict__ hh) {
  const int d = blockIdx.x, tid = threadIdx.x;
  const int wave = tid >> 6, lane = tid & 63;
  __shared__ float part[4][10];

  float acc[10];
#pragma unroll
  for (int t = 0; t < 10; t++) acc[t] = 0.f;
#pragma unroll
  for (int kk = 0; kk < 4; kk++) {
    const int k = kk * 256 + tid;
    const float wv = ga1_w[(size_t)d * 1024 + k];
#pragma unroll
    for (int t = 0; t < 10; t++) acc[t] = fmaf(wv, embs[t * 1024 + k], acc[t]);
  }
#pragma unroll
  for (int t = 0; t < 10; t++) {
#pragma unroll
    for (int off = 32; off > 0; off >>= 1) acc[t] += __shfl_xor(acc[t], off, 64);
  }
  if (lane == 0) {
#pragma unroll
    for (int t = 0; t < 10; t++) part[wave][t] = acc[t];
  }
  __syncthreads();
  if (tid < 10) {
    const float s = part[0][tid] + part[1][tid] + part[2][tid] + part[3][tid];
    hh[tid * 128 + d] = tanhf(s + ga1_b[d]);
  }
}

// ---------------------------------------------------------------------------
// ga2_k: g = hh.ga2_w + b -> softmax gammas (to ws) -> M -> Y_prob/Y_hat.
// Single small block (reads only ~6KB).
// ---------------------------------------------------------------------------
__launch_bounds__(256)
__global__ void ga2_k(const float* __restrict__ hh, const float* __restrict__ ga2_w,
                      const float* __restrict__ ga2_b, const float* __restrict__ embs,
                      const float* __restrict__ cls_w, const float* __restrict__ cls_b,
                      float* __restrict__ gam_ws, float* __restrict__ out) {
  __shared__ float g_s[10], gam_s[10];
  __shared__ float red[256];
  const int tid = threadIdx.x;
  const int wave = tid >> 6, lane = tid & 63;

  if (wave == 0) {
    for (int t = 0; t < 10; t++) {
      float s = hh[t * 128 + lane] * ga2_w[lane] + hh[t * 128 + 64 + lane] * ga2_w[64 + lane];
#pragma unroll
      for (int off = 32; off > 0; off >>= 1) s += __shfl_xor(s, off, 64);
      if (lane == 0) g_s[t] = s + ga2_b[0];
    }
  }
  __syncthreads();
  if (tid == 0) {
    float m = g_s[0];
    for (int t = 1; t < 10; t++) m = fmaxf(m, g_s[t]);
    float sum = 0.f;
    for (int t = 0; t < 10; t++) sum += expf(g_s[t] - m);
    for (int t = 0; t < 10; t++) {
      gam_s[t] = expf(g_s[t] - m) / sum;
      gam_ws[t] = gam_s[t];
    }
  }
  __syncthreads();

  // z = sum_k (sum_t gam[t]*embs[t,k]) * cls_w[k]
  float partl = 0.f;
  for (int k = tid; k < 1024; k += 256) {
    float a = 0.f;
#pragma unroll
    for (int t = 0; t < 10; t++) a = fmaf(gam_s[t], embs[t * 1024 + k], a);
    partl = fmaf(a, cls_w[k], partl);
  }
  red[tid] = partl;
  __syncthreads();
  for (int s = 128; s > 0; s >>= 1) {
    if (tid < s) red[tid] += red[tid + s];
    __syncthreads();
  }
  if (tid == 0) {
    const float z = red[0] + cls_b[0];
    const float yp = 1.f / (1.f + expf(-z));
    out[0] = yp;
    out[1] = (yp >= 0.5f) ? 1.f : 0.f;
  }
}

// ---------------------------------------------------------------------------
// A[n] = sum_t gammas[t] * betas[t,n]   (16 blocks)
// ---------------------------------------------------------------------------
__launch_bounds__(256)
__global__ void a_k(const float* __restrict__ betas, const float* __restrict__ gam,
                    float* __restrict__ outA) {
  const int n = blockIdx.x * 256 + threadIdx.x;
  float a = 0.f;
#pragma unroll
  for (int t = 0; t < 10; t++) a = fmaf(gam[t], betas[t * NINST + n], a);
  outA[n] = a;
}

// ---------------------------------------------------------------------------
extern "C" void kernel_launch(void* const* d_in, const int* in_sizes, int n_in,
                              void* d_out, int out_size, void* d_ws, size_t ws_size,
                              hipStream_t stream) {
  const float* x       = (const float*)d_in[0];
  const float* w1      = (const float*)d_in[2];
  const float* b1      = (const float*)d_in[3];
  const float* w2      = (const float*)d_in[4];
  const float* b2      = (const float*)d_in[5];
  const float* fc1_w   = (const float*)d_in[6];
  const float* fc1_b   = (const float*)d_in[7];
  const float* fc2_w   = (const float*)d_in[8];
  const float* fc2_b   = (const float*)d_in[9];
  const float* nbr_w   = (const float*)d_in[10];
  const float* nbr_b   = (const float*)d_in[11];
  const float* tmpl    = (const float*)d_in[12];
  const float* proto_w = (const float*)d_in[13];
  const float* proto_b = (const float*)d_in[14];
  const float* ga1_w   = (const float*)d_in[15];
  const float* ga1_b   = (const float*)d_in[16];
  const float* ga2_w   = (const float*)d_in[17];
  const float* ga2_b   = (const float*)d_in[18];
  const float* cls_w   = (const float*)d_in[19];
  const float* cls_b   = (const float*)d_in[20];
  float* out = (float*)d_out;

  char* w = (char*)d_ws;
  _Float16* embh = (_Float16*)w;  w += (size_t)4096 * 1728 * 2;
  _Float16* H1h  = (_Float16*)w;  w += (size_t)4096 * 512 * 2;
  _Float16* H2h  = (_Float16*)w;  w += (size_t)4096 * 1024 * 2;
  _Float16* TbH  = (_Float16*)w;  w += (size_t)4096 * 512 * 2;
  _Float16* PH   = (_Float16*)w;  w += (size_t)4096 * 1024 * 2;
  _Float16* w1tG = (_Float16*)w;  w += (size_t)48 * 64 * 2;
  _Float16* w2tG = (_Float16*)w;  w += (size_t)3 * 48 * 128 * 2;
  float* tl   = (float*)w;        w += (size_t)10 * NINST * 4;
  float* bet  = (float*)w;        w += (size_t)10 * NINST * 4;
  float* embs = (float*)w;        w += (size_t)10 * 1024 * 4;
  float* hhw  = (float*)w;        w += (size_t)10 * 128 * 4;
  float* gam  = (float*)w;        w += 256;

  xform_w12<<<64, 256, 0, stream>>>(w1, w2, w1tG, w2tG);
  conv_fused<<<NINST, 256, 0, stream>>>(x, w1tG, w2tG, b1, b2, embh);

  gemm_h<1><<<dim3(16, 64), 256, 0, stream>>>(embh, fc1_w, fc1_b, H1h, 1728, 1728, 1728, 512);
  gemm_h<1><<<dim3(16, 64), 256, 0, stream>>>(H1h, fc2_w, fc2_b, H2h, 512, 512, 512, 1024);
  gemm_h<2><<<dim3(16, 64), 256, 0, stream>>>(H2h, nbr_w, nbr_b, TbH, 512, 1024, 512, 512);
  nbhd_k<<<1024, 256, 0, stream>>>(H2h, TbH);
  gemm_h<2><<<dim3(32, 64), 256, 0, stream>>>(H2h, proto_w, proto_b, PH, 1024, 1024, 1024, 1024);
  templ_scores<<<1024, 256, 0, stream>>>(PH, tmpl, tl);
  softmax_rows<<<10, 256, 0, stream>>>(tl, bet, embs);
  embs_k<<<dim3(4, 16), 256, 0, stream>>>(bet, H2h, embs);
  ga1_k<<<128, 256, 0, stream>>>(embs, ga1_w, ga1_b, hhw);
  ga2_k<<<1, 256, 0, stream>>>(hhw, ga2_w, ga2_b, embs, cls_w, cls_b, gam, out);
  a_k<<<16, 256, 0, stream>>>(bet, gam, out + 2);
}